// Round 1
// baseline (2784.577 us; speedup 1.0000x reference)
//
#include <hip/hip_runtime.h>
#include <hip/hip_bf16.h>
#include <math.h>

#define N_NODES 20000
#define N_EDGES 320000
#define DIN 50
#define HID 1024
#define NC3 726   // 6*121
#define NCLS 121

// ---------------- small utility kernels ----------------

__global__ void zero_int_kernel(int* p, int n) {
    int i = blockIdx.x * blockDim.x + threadIdx.x;
    if (i < n) p[i] = 0;
}

__global__ void count_deg_kernel(const int* __restrict__ col, int* __restrict__ deg, int e) {
    int i = blockIdx.x * blockDim.x + threadIdx.x;
    if (i < e) atomicAdd(&deg[col[i]], 1);
}

__global__ void compute_dis_kernel(const int* __restrict__ deg, float* __restrict__ dis, int n) {
    int i = blockIdx.x * blockDim.x + threadIdx.x;
    if (i < n) {
        int d = deg[i];
        dis[i] = d > 0 ? rsqrtf((float)d) : 0.0f;
    }
}

__global__ void compute_norm_kernel(const int* __restrict__ row, const int* __restrict__ col,
                                    const float* __restrict__ dis, float* __restrict__ norm, int e) {
    int i = blockIdx.x * blockDim.x + threadIdx.x;
    if (i < e) norm[i] = dis[row[i]] * dis[col[i]];
}

// single-block exclusive scan of deg -> offs (and cursor copy)
__global__ __launch_bounds__(1024) void scan_kernel(const int* __restrict__ deg,
                                                    int* __restrict__ offs,
                                                    int* __restrict__ cursor,
                                                    int n, int total) {
    __shared__ int part[1024];
    int t = threadIdx.x;
    const int CH = (n + 1023) / 1024;
    int base0 = t * CH;
    int s = 0;
    for (int i = 0; i < CH; ++i) {
        int idx = base0 + i;
        if (idx < n) s += deg[idx];
    }
    part[t] = s;
    __syncthreads();
    for (int d = 1; d < 1024; d <<= 1) {
        int v = (t >= d) ? part[t - d] : 0;
        __syncthreads();
        part[t] += v;
        __syncthreads();
    }
    int run = part[t] - s;  // exclusive prefix of this chunk
    for (int i = 0; i < CH; ++i) {
        int idx = base0 + i;
        if (idx < n) {
            offs[idx] = run;
            cursor[idx] = run;
            run += deg[idx];
        }
    }
    if (t == 1023) offs[n] = total;
}

__global__ void scatter_kernel(const int* __restrict__ row, const int* __restrict__ col,
                               const float* __restrict__ norm, int* __restrict__ cursor,
                               int* __restrict__ csr_src, float* __restrict__ csr_w, int e) {
    int i = blockIdx.x * blockDim.x + threadIdx.x;
    if (i < e) {
        int c = col[i];
        int pos = atomicAdd(&cursor[c], 1);
        csr_src[pos] = row[i];
        csr_w[pos] = norm[i];
    }
}

// ---------------- fp32 tiled GEMM: C[M,N] = A[M,K] @ B[K,N] ----------------
#define BM 128
#define BN 128
#define BK 16

__global__ __launch_bounds__(256) void sgemm_kernel(const float* __restrict__ A,
                                                    const float* __restrict__ B,
                                                    float* __restrict__ C,
                                                    int M, int N, int K) {
    __shared__ float As[BK][BM + 4];
    __shared__ float Bs[BK][BN + 4];

    const int bm = blockIdx.y * BM;
    const int bn = blockIdx.x * BN;
    const int tid = threadIdx.x;
    const int tm = tid / 16;   // 0..15
    const int tn = tid % 16;   // 0..15

    const int a_r = tid / 4;          // 0..63
    const int a_c = (tid % 4) * 4;    // 0,4,8,12
    const int b_r = tid / 32;         // 0..7
    const int b_c = (tid % 32) * 4;   // 0..124

    const bool kvec = ((K & 3) == 0);
    const bool nvec = ((N & 3) == 0);

    float acc[8][8];
#pragma unroll
    for (int i = 0; i < 8; ++i)
#pragma unroll
        for (int j = 0; j < 8; ++j) acc[i][j] = 0.0f;

    for (int k0 = 0; k0 < K; k0 += BK) {
        // ---- load A tile (BM x BK), store transposed into As[k][m] ----
#pragma unroll
        for (int half = 0; half < 2; ++half) {
            int r = a_r + half * 64;
            int gm = bm + r;
            float v0 = 0, v1 = 0, v2 = 0, v3 = 0;
            int gk = k0 + a_c;
            if (gm < M) {
                if (kvec && gk + 3 < K) {
                    float4 v = *(const float4*)&A[(size_t)gm * K + gk];
                    v0 = v.x; v1 = v.y; v2 = v.z; v3 = v.w;
                } else {
                    if (gk + 0 < K) v0 = A[(size_t)gm * K + gk + 0];
                    if (gk + 1 < K) v1 = A[(size_t)gm * K + gk + 1];
                    if (gk + 2 < K) v2 = A[(size_t)gm * K + gk + 2];
                    if (gk + 3 < K) v3 = A[(size_t)gm * K + gk + 3];
                }
            }
            As[a_c + 0][r] = v0;
            As[a_c + 1][r] = v1;
            As[a_c + 2][r] = v2;
            As[a_c + 3][r] = v3;
        }
        // ---- load B tile (BK x BN) ----
#pragma unroll
        for (int half = 0; half < 2; ++half) {
            int r = b_r + half * 8;
            int gk = k0 + r;
            int gn = bn + b_c;
            float v0 = 0, v1 = 0, v2 = 0, v3 = 0;
            if (gk < K) {
                if (nvec && gn + 3 < N) {
                    float4 v = *(const float4*)&B[(size_t)gk * N + gn];
                    v0 = v.x; v1 = v.y; v2 = v.z; v3 = v.w;
                } else {
                    if (gn + 0 < N) v0 = B[(size_t)gk * N + gn + 0];
                    if (gn + 1 < N) v1 = B[(size_t)gk * N + gn + 1];
                    if (gn + 2 < N) v2 = B[(size_t)gk * N + gn + 2];
                    if (gn + 3 < N) v3 = B[(size_t)gk * N + gn + 3];
                }
            }
            Bs[r][b_c + 0] = v0;
            Bs[r][b_c + 1] = v1;
            Bs[r][b_c + 2] = v2;
            Bs[r][b_c + 3] = v3;
        }
        __syncthreads();

#pragma unroll
        for (int kk = 0; kk < BK; ++kk) {
            float a[8], b[8];
#pragma unroll
            for (int i = 0; i < 8; ++i) a[i] = As[kk][tm * 8 + i];
#pragma unroll
            for (int j = 0; j < 8; ++j) b[j] = Bs[kk][tn * 8 + j];
#pragma unroll
            for (int i = 0; i < 8; ++i)
#pragma unroll
                for (int j = 0; j < 8; ++j) acc[i][j] = fmaf(a[i], b[j], acc[i][j]);
        }
        __syncthreads();
    }

    // ---- store ----
#pragma unroll
    for (int i = 0; i < 8; ++i) {
        int gm = bm + tm * 8 + i;
        if (gm >= M) continue;
        if (nvec) {
#pragma unroll
            for (int j = 0; j < 8; j += 4) {
                int gn = bn + tn * 8 + j;
                if (gn + 3 < N) {
                    float4 v;
                    v.x = acc[i][j + 0]; v.y = acc[i][j + 1];
                    v.z = acc[i][j + 2]; v.w = acc[i][j + 3];
                    *(float4*)&C[(size_t)gm * N + gn] = v;
                } else {
                    for (int jj = 0; jj < 4; ++jj) {
                        int g = gn + jj;
                        if (g < N) C[(size_t)gm * N + g] = acc[i][j + jj];
                    }
                }
            }
        } else {
#pragma unroll
            for (int j = 0; j < 8; ++j) {
                int gn = bn + tn * 8 + j;
                if (gn < N) C[(size_t)gm * N + gn] = acc[i][j];
            }
        }
    }
}

// ---------------- aggregation (F = 1024, float4), optional skip + elu ----------------
__global__ __launch_bounds__(256) void agg1024_kernel(const float4* __restrict__ XW,
                                                      const float4* __restrict__ skip,
                                                      const int* __restrict__ offs,
                                                      const int* __restrict__ csr_src,
                                                      const float* __restrict__ csr_w,
                                                      float4* __restrict__ out,
                                                      int apply_elu) {
    int n = blockIdx.x;
    int t = threadIdx.x;  // 0..255, covers 1024 floats as float4
    float ax = 0, ay = 0, az = 0, aw = 0;
    int p0 = offs[n], p1 = offs[n + 1];
    for (int p = p0; p < p1; ++p) {
        int s = csr_src[p];
        float w = csr_w[p];
        float4 v = XW[(size_t)s * 256 + t];
        ax = fmaf(w, v.x, ax);
        ay = fmaf(w, v.y, ay);
        az = fmaf(w, v.z, az);
        aw = fmaf(w, v.w, aw);
    }
    if (skip) {
        float4 sv = skip[(size_t)n * 256 + t];
        ax += sv.x; ay += sv.y; az += sv.z; aw += sv.w;
    }
    if (apply_elu) {
        ax = ax > 0 ? ax : expf(ax) - 1.0f;
        ay = ay > 0 ? ay : expf(ay) - 1.0f;
        az = az > 0 ? az : expf(az) - 1.0f;
        aw = aw > 0 ? aw : expf(aw) - 1.0f;
    }
    float4 o; o.x = ax; o.y = ay; o.z = az; o.w = aw;
    out[(size_t)n * 256 + t] = o;
}

// ---------------- layer-3 aggregation + skip + head mean ----------------
__global__ __launch_bounds__(128) void agg3_mean_kernel(const float* __restrict__ T3,
                                                        const float* __restrict__ Sk3,
                                                        const int* __restrict__ offs,
                                                        const int* __restrict__ csr_src,
                                                        const float* __restrict__ csr_w,
                                                        float* __restrict__ out) {
    int n = blockIdx.x;
    int c = threadIdx.x;
    if (c >= NCLS) return;
    float acc = 0.0f;
    int p0 = offs[n], p1 = offs[n + 1];
    for (int p = p0; p < p1; ++p) {
        int s = csr_src[p];
        float w = csr_w[p];
        const float* tr = T3 + (size_t)s * NC3 + c;
        float vs = tr[0] + tr[121] + tr[242] + tr[363] + tr[484] + tr[605];
        acc = fmaf(w, vs, acc);
    }
    const float* sr = Sk3 + (size_t)n * NC3 + c;
    acc += sr[0] + sr[121] + sr[242] + sr[363] + sr[484] + sr[605];
    out[(size_t)n * NCLS + c] = acc * (1.0f / 6.0f);
}

// ---------------- launch ----------------

static inline size_t align_up(size_t x, size_t a) { return (x + a - 1) & ~(a - 1); }

extern "C" void kernel_launch(void* const* d_in, const int* in_sizes, int n_in,
                              void* d_out, int out_size, void* d_ws, size_t ws_size,
                              hipStream_t stream) {
    const float* X  = (const float*)d_in[0];
    const int* erow = (const int*)d_in[1];            // edge_index[0]
    const int* ecol = (const int*)d_in[1] + N_EDGES;  // edge_index[1]
    const float* W1 = (const float*)d_in[2];
    const float* W2 = (const float*)d_in[3];
    const float* S2 = (const float*)d_in[4];
    const float* W3 = (const float*)d_in[5];
    const float* S3 = (const float*)d_in[6];
    float* out = (float*)d_out;

    // workspace carve-up
    char* w = (char*)d_ws;
    int* deg    = (int*)w;              w += align_up((size_t)N_NODES * 4, 256);
    int* offs   = (int*)w;              w += align_up((size_t)(N_NODES + 1) * 4, 256);
    int* cursor = (int*)w;              w += align_up((size_t)N_NODES * 4, 256);
    int* csr_src = (int*)w;             w += align_up((size_t)N_EDGES * 4, 256);
    float* dis  = (float*)w;            w += align_up((size_t)N_NODES * 4, 256);
    float* norm = (float*)w;            w += align_up((size_t)N_EDGES * 4, 256);
    float* csr_w = (float*)w;           w += align_up((size_t)N_EDGES * 4, 256);
    float* P = (float*)w;               w += align_up((size_t)N_NODES * HID * 4, 256);
    float* Q = (float*)w;               w += align_up((size_t)N_NODES * HID * 4, 256);
    float* R = (float*)w;               w += align_up((size_t)N_NODES * HID * 4, 256);

    const int TB = 256;
    int nb_n = (N_NODES + TB - 1) / TB;
    int nb_e = (N_EDGES + TB - 1) / TB;

    // 1. degree / norm / CSR build
    zero_int_kernel<<<nb_n, TB, 0, stream>>>(deg, N_NODES);
    count_deg_kernel<<<nb_e, TB, 0, stream>>>(ecol, deg, N_EDGES);
    compute_dis_kernel<<<nb_n, TB, 0, stream>>>(deg, dis, N_NODES);
    compute_norm_kernel<<<nb_e, TB, 0, stream>>>(erow, ecol, dis, norm, N_EDGES);
    scan_kernel<<<1, 1024, 0, stream>>>(deg, offs, cursor, N_NODES, N_EDGES);
    scatter_kernel<<<nb_e, TB, 0, stream>>>(erow, ecol, norm, cursor, csr_src, csr_w, N_EDGES);

    // 2. layer 1: XW1 = X @ W1 ; h1 = elu(agg(XW1))  -> Q
    {
        dim3 grid((HID + BN - 1) / BN, (N_NODES + BM - 1) / BM);
        sgemm_kernel<<<grid, 256, 0, stream>>>(X, W1, P, N_NODES, HID, DIN);
    }
    agg1024_kernel<<<N_NODES, 256, 0, stream>>>((const float4*)P, nullptr, offs, csr_src, csr_w,
                                                (float4*)Q, 1);

    // 3. layer 2: T2 = h1@W2 -> P ; S = h1@S2 -> R ; h2 = elu(agg(T2) + S) -> Q
    {
        dim3 grid((HID + BN - 1) / BN, (N_NODES + BM - 1) / BM);
        sgemm_kernel<<<grid, 256, 0, stream>>>(Q, W2, P, N_NODES, HID, HID);
        sgemm_kernel<<<grid, 256, 0, stream>>>(Q, S2, R, N_NODES, HID, HID);
    }
    agg1024_kernel<<<N_NODES, 256, 0, stream>>>((const float4*)P, (const float4*)R, offs, csr_src,
                                                csr_w, (float4*)Q, 1);

    // 4. layer 3: T3 = h2@W3 -> P ; Sk3 = h2@S3 -> R ; out = mean_heads(agg(T3) + Sk3)
    {
        dim3 grid((NC3 + BN - 1) / BN, (N_NODES + BM - 1) / BM);
        sgemm_kernel<<<grid, 256, 0, stream>>>(Q, W3, P, N_NODES, NC3, HID);
        sgemm_kernel<<<grid, 256, 0, stream>>>(Q, S3, R, N_NODES, NC3, HID);
    }
    agg3_mean_kernel<<<N_NODES, 128, 0, stream>>>(P, R, offs, csr_src, csr_w, out);
}

// Round 2
// 1277.456 us; speedup vs baseline: 2.1798x; 2.1798x over previous
//
#include <hip/hip_runtime.h>
#include <hip/hip_bf16.h>
#include <math.h>

#define N_NODES 20000
#define N_EDGES 320000
#define DIN 50
#define HID 1024
#define NC3 726   // 6*121
#define NCLS 121

typedef __attribute__((ext_vector_type(8))) short short8;
typedef __attribute__((ext_vector_type(4))) float floatx4;

__device__ __forceinline__ unsigned short f2bf(float v) {
    __hip_bfloat16 h = __float2bfloat16(v);
    return __builtin_bit_cast(unsigned short, h);
}
__device__ __forceinline__ float bf2f(unsigned short u) {
    __hip_bfloat16 h = __builtin_bit_cast(__hip_bfloat16, u);
    return __bfloat162float(h);
}

// ---------------- small utility kernels ----------------

__global__ void zero_int_kernel(int* p, int n) {
    int i = blockIdx.x * blockDim.x + threadIdx.x;
    if (i < n) p[i] = 0;
}

__global__ void count_deg_kernel(const int* __restrict__ col, int* __restrict__ deg, int e) {
    int i = blockIdx.x * blockDim.x + threadIdx.x;
    if (i < e) atomicAdd(&deg[col[i]], 1);
}

__global__ void compute_dis_kernel(const int* __restrict__ deg, float* __restrict__ dis, int n) {
    int i = blockIdx.x * blockDim.x + threadIdx.x;
    if (i < n) {
        int d = deg[i];
        dis[i] = d > 0 ? rsqrtf((float)d) : 0.0f;
    }
}

__global__ void compute_norm_kernel(const int* __restrict__ row, const int* __restrict__ col,
                                    const float* __restrict__ dis, float* __restrict__ norm, int e) {
    int i = blockIdx.x * blockDim.x + threadIdx.x;
    if (i < e) norm[i] = dis[row[i]] * dis[col[i]];
}

// single-block exclusive scan of deg -> offs (and cursor copy)
__global__ __launch_bounds__(1024) void scan_kernel(const int* __restrict__ deg,
                                                    int* __restrict__ offs,
                                                    int* __restrict__ cursor,
                                                    int n, int total) {
    __shared__ int part[1024];
    int t = threadIdx.x;
    const int CH = (n + 1023) / 1024;
    int base0 = t * CH;
    int s = 0;
    for (int i = 0; i < CH; ++i) {
        int idx = base0 + i;
        if (idx < n) s += deg[idx];
    }
    part[t] = s;
    __syncthreads();
    for (int d = 1; d < 1024; d <<= 1) {
        int v = (t >= d) ? part[t - d] : 0;
        __syncthreads();
        part[t] += v;
        __syncthreads();
    }
    int run = part[t] - s;  // exclusive prefix of this chunk
    for (int i = 0; i < CH; ++i) {
        int idx = base0 + i;
        if (idx < n) {
            offs[idx] = run;
            cursor[idx] = run;
            run += deg[idx];
        }
    }
    if (t == 1023) offs[n] = total;
}

__global__ void scatter_kernel(const int* __restrict__ row, const int* __restrict__ col,
                               const float* __restrict__ norm, int* __restrict__ cursor,
                               int* __restrict__ csr_src, float* __restrict__ csr_w, int e) {
    int i = blockIdx.x * blockDim.x + threadIdx.x;
    if (i < e) {
        int c = col[i];
        int pos = atomicAdd(&cursor[c], 1);
        csr_src[pos] = row[i];
        csr_w[pos] = norm[i];
    }
}

// ---------------- weight convert: W[K][N] fp32 -> Wt_hi/Wt_lo [N][K] bf16 ----------------
__global__ void convert_wt_kernel(const float* __restrict__ W,
                                  unsigned short* __restrict__ Th,
                                  unsigned short* __restrict__ Tl,
                                  int K, int N) {
    int i = blockIdx.x * blockDim.x + threadIdx.x;
    if (i >= K * N) return;
    int k = i / N, n = i - k * N;
    float v = W[i];
    unsigned short h = f2bf(v);
    float rem = v - bf2f(h);
    Th[n * K + k] = h;
    Tl[n * K + k] = f2bf(rem);
}

// ---------------- fp32 tiled GEMM (layer 1 only, K=50) ----------------
#define BM 128
#define BN 128
#define BK 16

__global__ __launch_bounds__(256) void sgemm_kernel(const float* __restrict__ A,
                                                    const float* __restrict__ B,
                                                    float* __restrict__ C,
                                                    int M, int N, int K) {
    __shared__ float As[BK][BM + 4];
    __shared__ float Bs[BK][BN + 4];

    const int bm = blockIdx.y * BM;
    const int bn = blockIdx.x * BN;
    const int tid = threadIdx.x;
    const int tm = tid / 16;
    const int tn = tid % 16;

    const int a_r = tid / 4;
    const int a_c = (tid % 4) * 4;
    const int b_r = tid / 32;
    const int b_c = (tid % 32) * 4;

    const bool kvec = ((K & 3) == 0);
    const bool nvec = ((N & 3) == 0);

    float acc[8][8];
#pragma unroll
    for (int i = 0; i < 8; ++i)
#pragma unroll
        for (int j = 0; j < 8; ++j) acc[i][j] = 0.0f;

    for (int k0 = 0; k0 < K; k0 += BK) {
#pragma unroll
        for (int half = 0; half < 2; ++half) {
            int r = a_r + half * 64;
            int gm = bm + r;
            float v0 = 0, v1 = 0, v2 = 0, v3 = 0;
            int gk = k0 + a_c;
            if (gm < M) {
                if (kvec && gk + 3 < K) {
                    float4 v = *(const float4*)&A[(size_t)gm * K + gk];
                    v0 = v.x; v1 = v.y; v2 = v.z; v3 = v.w;
                } else {
                    if (gk + 0 < K) v0 = A[(size_t)gm * K + gk + 0];
                    if (gk + 1 < K) v1 = A[(size_t)gm * K + gk + 1];
                    if (gk + 2 < K) v2 = A[(size_t)gm * K + gk + 2];
                    if (gk + 3 < K) v3 = A[(size_t)gm * K + gk + 3];
                }
            }
            As[a_c + 0][r] = v0;
            As[a_c + 1][r] = v1;
            As[a_c + 2][r] = v2;
            As[a_c + 3][r] = v3;
        }
#pragma unroll
        for (int half = 0; half < 2; ++half) {
            int r = b_r + half * 8;
            int gk = k0 + r;
            int gn = bn + b_c;
            float v0 = 0, v1 = 0, v2 = 0, v3 = 0;
            if (gk < K) {
                if (nvec && gn + 3 < N) {
                    float4 v = *(const float4*)&B[(size_t)gk * N + gn];
                    v0 = v.x; v1 = v.y; v2 = v.z; v3 = v.w;
                } else {
                    if (gn + 0 < N) v0 = B[(size_t)gk * N + gn + 0];
                    if (gn + 1 < N) v1 = B[(size_t)gk * N + gn + 1];
                    if (gn + 2 < N) v2 = B[(size_t)gk * N + gn + 2];
                    if (gn + 3 < N) v3 = B[(size_t)gk * N + gn + 3];
                }
            }
            Bs[r][b_c + 0] = v0;
            Bs[r][b_c + 1] = v1;
            Bs[r][b_c + 2] = v2;
            Bs[r][b_c + 3] = v3;
        }
        __syncthreads();

#pragma unroll
        for (int kk = 0; kk < BK; ++kk) {
            float a[8], b[8];
#pragma unroll
            for (int i = 0; i < 8; ++i) a[i] = As[kk][tm * 8 + i];
#pragma unroll
            for (int j = 0; j < 8; ++j) b[j] = Bs[kk][tn * 8 + j];
#pragma unroll
            for (int i = 0; i < 8; ++i)
#pragma unroll
                for (int j = 0; j < 8; ++j) acc[i][j] = fmaf(a[i], b[j], acc[i][j]);
        }
        __syncthreads();
    }

#pragma unroll
    for (int i = 0; i < 8; ++i) {
        int gm = bm + tm * 8 + i;
        if (gm >= M) continue;
#pragma unroll
        for (int j = 0; j < 8; j += 4) {
            int gn = bn + tn * 8 + j;
            if (nvec && gn + 3 < N) {
                float4 v;
                v.x = acc[i][j + 0]; v.y = acc[i][j + 1];
                v.z = acc[i][j + 2]; v.w = acc[i][j + 3];
                *(float4*)&C[(size_t)gm * N + gn] = v;
            } else {
                for (int jj = 0; jj < 4; ++jj) {
                    int g = gn + jj;
                    if (g < N) C[(size_t)gm * N + g] = acc[i][j + jj];
                }
            }
        }
    }
}

// ---------------- split-bf16 MFMA GEMM ----------------
// C[M][N] = A @ B  computed as Ah@Bh + Al@Bh + Ah@Bl  (fp32 accumulate)
// A given as Ah/Al [M][K] bf16 row-major; B given as Bth/Btl [N][K] bf16 (transposed).
// Block tile 128x128, BK=32, 4 waves (2x2), each wave 64x64 = 4x4 MFMA 16x16x32 tiles.

#define GBM 128
#define GBN 128
#define GBK 32
#define LDK 40  // padded K stride in LDS (+8 bf16 = 16B pad -> conflict-free-ish)

__global__ __launch_bounds__(256, 2) void mfma_gemm_kernel(
        const unsigned short* __restrict__ Ah, const unsigned short* __restrict__ Al,
        const unsigned short* __restrict__ Bth, const unsigned short* __restrict__ Btl,
        float* __restrict__ C, int M, int N, int K) {
    __shared__ __align__(16) unsigned short sAh[GBM][LDK];
    __shared__ __align__(16) unsigned short sAl[GBM][LDK];
    __shared__ __align__(16) unsigned short sBh[GBN][LDK];
    __shared__ __align__(16) unsigned short sBl[GBN][LDK];

    const int tid = threadIdx.x;
    const int lane = tid & 63;
    const int wave = tid >> 6;
    const int wm = wave >> 1;        // 0..1
    const int wn = wave & 1;         // 0..1
    const int bm = blockIdx.y * GBM;
    const int bn = blockIdx.x * GBN;

    // staging mapping: per pass, thread covers row r=(tid>>2)+64*pass, kchunk=(tid&3)*8
    const int st_r = tid >> 2;          // 0..63
    const int st_kc = (tid & 3) * 8;    // 0,8,16,24

    // fragment mapping
    const int frow = lane & 15;
    const int fkc = (lane >> 4) * 8;

    floatx4 acc[4][4];
#pragma unroll
    for (int i = 0; i < 4; ++i)
#pragma unroll
        for (int j = 0; j < 4; ++j) acc[i][j] = (floatx4){0.f, 0.f, 0.f, 0.f};

    uint4 rah[2], ral[2], rbh[2], rbl[2];

    // prologue: load tile k0=0 into registers
    {
        const int k0 = 0;
#pragma unroll
        for (int p = 0; p < 2; ++p) {
            int gm = bm + st_r + p * 64;
            bool ap = gm < M;
            size_t ao = (size_t)gm * K + k0 + st_kc;
            rah[p] = ap ? *(const uint4*)&Ah[ao] : (uint4){0, 0, 0, 0};
            ral[p] = ap ? *(const uint4*)&Al[ao] : (uint4){0, 0, 0, 0};
            int gn = bn + st_r + p * 64;
            bool bp = gn < N;
            size_t bo = (size_t)gn * K + k0 + st_kc;
            rbh[p] = bp ? *(const uint4*)&Bth[bo] : (uint4){0, 0, 0, 0};
            rbl[p] = bp ? *(const uint4*)&Btl[bo] : (uint4){0, 0, 0, 0};
        }
    }

    for (int k0 = 0; k0 < K; k0 += GBK) {
        __syncthreads();  // LDS safe to overwrite
#pragma unroll
        for (int p = 0; p < 2; ++p) {
            int r = st_r + p * 64;
            *(uint4*)&sAh[r][st_kc] = rah[p];
            *(uint4*)&sAl[r][st_kc] = ral[p];
            *(uint4*)&sBh[r][st_kc] = rbh[p];
            *(uint4*)&sBl[r][st_kc] = rbl[p];
        }
        __syncthreads();

        // prefetch next tile into registers (overlaps with MFMA below)
        int kn = k0 + GBK;
        if (kn < K) {
#pragma unroll
            for (int p = 0; p < 2; ++p) {
                int gm = bm + st_r + p * 64;
                bool ap = gm < M;
                size_t ao = (size_t)gm * K + kn + st_kc;
                rah[p] = ap ? *(const uint4*)&Ah[ao] : (uint4){0, 0, 0, 0};
                ral[p] = ap ? *(const uint4*)&Al[ao] : (uint4){0, 0, 0, 0};
                int gn = bn + st_r + p * 64;
                bool bp = gn < N;
                size_t bo = (size_t)gn * K + kn + st_kc;
                rbh[p] = bp ? *(const uint4*)&Bth[bo] : (uint4){0, 0, 0, 0};
                rbl[p] = bp ? *(const uint4*)&Btl[bo] : (uint4){0, 0, 0, 0};
            }
        }

        short8 fah[4], fal[4], fbh[4], fbl[4];
#pragma unroll
        for (int i = 0; i < 4; ++i) {
            int r = wm * 64 + i * 16 + frow;
            fah[i] = *(const short8*)&sAh[r][fkc];
            fal[i] = *(const short8*)&sAl[r][fkc];
        }
#pragma unroll
        for (int j = 0; j < 4; ++j) {
            int r = wn * 64 + j * 16 + frow;
            fbh[j] = *(const short8*)&sBh[r][fkc];
            fbl[j] = *(const short8*)&sBl[r][fkc];
        }
#pragma unroll
        for (int i = 0; i < 4; ++i)
#pragma unroll
            for (int j = 0; j < 4; ++j) {
                acc[i][j] = __builtin_amdgcn_mfma_f32_16x16x32_bf16(fah[i], fbh[j], acc[i][j], 0, 0, 0);
                acc[i][j] = __builtin_amdgcn_mfma_f32_16x16x32_bf16(fal[i], fbh[j], acc[i][j], 0, 0, 0);
                acc[i][j] = __builtin_amdgcn_mfma_f32_16x16x32_bf16(fah[i], fbl[j], acc[i][j], 0, 0, 0);
            }
    }

    // store: C/D layout col=lane&15, row=(lane>>4)*4+reg
    const int c_r0 = (lane >> 4) * 4;
    const int c_c = lane & 15;
#pragma unroll
    for (int i = 0; i < 4; ++i)
#pragma unroll
        for (int j = 0; j < 4; ++j) {
            int gn = bn + wn * 64 + j * 16 + c_c;
            if (gn >= N) continue;
#pragma unroll
            for (int r = 0; r < 4; ++r) {
                int gm = bm + wm * 64 + i * 16 + c_r0 + r;
                if (gm < M) C[(size_t)gm * N + gn] = acc[i][j][r];
            }
        }
}

// ---------------- aggregation (F = 1024, float4) -> elu -> bf16 hi/lo split ----------------
__global__ __launch_bounds__(256) void agg1024_kernel(const float4* __restrict__ XW,
                                                      const float4* __restrict__ skip,
                                                      const int* __restrict__ offs,
                                                      const int* __restrict__ csr_src,
                                                      const float* __restrict__ csr_w,
                                                      unsigned short* __restrict__ outh,
                                                      unsigned short* __restrict__ outl) {
    int n = blockIdx.x;
    int t = threadIdx.x;  // 0..255
    float a[4] = {0, 0, 0, 0};
    int p0 = offs[n], p1 = offs[n + 1];
    for (int p = p0; p < p1; ++p) {
        int s = csr_src[p];
        float w = csr_w[p];
        float4 v = XW[(size_t)s * 256 + t];
        a[0] = fmaf(w, v.x, a[0]);
        a[1] = fmaf(w, v.y, a[1]);
        a[2] = fmaf(w, v.z, a[2]);
        a[3] = fmaf(w, v.w, a[3]);
    }
    if (skip) {
        float4 sv = skip[(size_t)n * 256 + t];
        a[0] += sv.x; a[1] += sv.y; a[2] += sv.z; a[3] += sv.w;
    }
    ushort4 hv, lv;
    unsigned short* hp = (unsigned short*)&hv;
    unsigned short* lp = (unsigned short*)&lv;
#pragma unroll
    for (int j = 0; j < 4; ++j) {
        float v = a[j];
        v = v > 0 ? v : expf(v) - 1.0f;  // elu
        unsigned short h = f2bf(v);
        hp[j] = h;
        lp[j] = f2bf(v - bf2f(h));
    }
    *(ushort4*)&outh[(size_t)n * 1024 + t * 4] = hv;
    *(ushort4*)&outl[(size_t)n * 1024 + t * 4] = lv;
}

// ---------------- layer-3 aggregation + skip + head mean ----------------
__global__ __launch_bounds__(128) void agg3_mean_kernel(const float* __restrict__ T3,
                                                        const float* __restrict__ Sk3,
                                                        const int* __restrict__ offs,
                                                        const int* __restrict__ csr_src,
                                                        const float* __restrict__ csr_w,
                                                        float* __restrict__ out) {
    int n = blockIdx.x;
    int c = threadIdx.x;
    if (c >= NCLS) return;
    float acc = 0.0f;
    int p0 = offs[n], p1 = offs[n + 1];
    for (int p = p0; p < p1; ++p) {
        int s = csr_src[p];
        float w = csr_w[p];
        const float* tr = T3 + (size_t)s * NC3 + c;
        float vs = tr[0] + tr[121] + tr[242] + tr[363] + tr[484] + tr[605];
        acc = fmaf(w, vs, acc);
    }
    const float* sr = Sk3 + (size_t)n * NC3 + c;
    acc += sr[0] + sr[121] + sr[242] + sr[363] + sr[484] + sr[605];
    out[(size_t)n * NCLS + c] = acc * (1.0f / 6.0f);
}

// ---------------- launch ----------------

static inline size_t align_up(size_t x, size_t a) { return (x + a - 1) & ~(a - 1); }

extern "C" void kernel_launch(void* const* d_in, const int* in_sizes, int n_in,
                              void* d_out, int out_size, void* d_ws, size_t ws_size,
                              hipStream_t stream) {
    const float* X  = (const float*)d_in[0];
    const int* erow = (const int*)d_in[1];            // edge_index[0]
    const int* ecol = (const int*)d_in[1] + N_EDGES;  // edge_index[1]
    const float* W1 = (const float*)d_in[2];
    const float* W2 = (const float*)d_in[3];
    const float* S2 = (const float*)d_in[4];
    const float* W3 = (const float*)d_in[5];
    const float* S3 = (const float*)d_in[6];
    float* out = (float*)d_out;

    // workspace carve-up
    char* w = (char*)d_ws;
    int* deg     = (int*)w;             w += align_up((size_t)N_NODES * 4, 256);
    int* offs    = (int*)w;             w += align_up((size_t)(N_NODES + 1) * 4, 256);
    int* cursor  = (int*)w;             w += align_up((size_t)N_NODES * 4, 256);
    int* csr_src = (int*)w;             w += align_up((size_t)N_EDGES * 4, 256);
    float* dis   = (float*)w;           w += align_up((size_t)N_NODES * 4, 256);
    float* norm  = (float*)w;           w += align_up((size_t)N_EDGES * 4, 256);
    float* csr_w = (float*)w;           w += align_up((size_t)N_EDGES * 4, 256);
    float* P = (float*)w;               w += align_up((size_t)N_NODES * HID * 4, 256);
    float* R = (float*)w;               w += align_up((size_t)N_NODES * HID * 4, 256);
    unsigned short* Hh = (unsigned short*)w;  w += align_up((size_t)N_NODES * HID * 2, 256);
    unsigned short* Hl = (unsigned short*)w;  w += align_up((size_t)N_NODES * HID * 2, 256);
    unsigned short* W2h = (unsigned short*)w; w += align_up((size_t)HID * HID * 2, 256);
    unsigned short* W2l = (unsigned short*)w; w += align_up((size_t)HID * HID * 2, 256);
    unsigned short* S2h = (unsigned short*)w; w += align_up((size_t)HID * HID * 2, 256);
    unsigned short* S2l = (unsigned short*)w; w += align_up((size_t)HID * HID * 2, 256);
    unsigned short* W3h = (unsigned short*)w; w += align_up((size_t)HID * NC3 * 2, 256);
    unsigned short* W3l = (unsigned short*)w; w += align_up((size_t)HID * NC3 * 2, 256);
    unsigned short* S3h = (unsigned short*)w; w += align_up((size_t)HID * NC3 * 2, 256);
    unsigned short* S3l = (unsigned short*)w; w += align_up((size_t)HID * NC3 * 2, 256);

    const int TB = 256;
    int nb_n = (N_NODES + TB - 1) / TB;
    int nb_e = (N_EDGES + TB - 1) / TB;

    // 1. degree / norm / CSR build
    zero_int_kernel<<<nb_n, TB, 0, stream>>>(deg, N_NODES);
    count_deg_kernel<<<nb_e, TB, 0, stream>>>(ecol, deg, N_EDGES);
    compute_dis_kernel<<<nb_n, TB, 0, stream>>>(deg, dis, N_NODES);
    compute_norm_kernel<<<nb_e, TB, 0, stream>>>(erow, ecol, dis, norm, N_EDGES);
    scan_kernel<<<1, 1024, 0, stream>>>(deg, offs, cursor, N_NODES, N_EDGES);
    scatter_kernel<<<nb_e, TB, 0, stream>>>(erow, ecol, norm, cursor, csr_src, csr_w, N_EDGES);

    // 1b. weight conversion (transposed, bf16 hi/lo)
    {
        int n22 = HID * HID, n33 = HID * NC3;
        convert_wt_kernel<<<(n22 + 255) / 256, 256, 0, stream>>>(W2, W2h, W2l, HID, HID);
        convert_wt_kernel<<<(n22 + 255) / 256, 256, 0, stream>>>(S2, S2h, S2l, HID, HID);
        convert_wt_kernel<<<(n33 + 255) / 256, 256, 0, stream>>>(W3, W3h, W3l, HID, NC3);
        convert_wt_kernel<<<(n33 + 255) / 256, 256, 0, stream>>>(S3, S3h, S3l, HID, NC3);
    }

    // 2. layer 1 (fp32 VALU GEMM, K=50): P = X @ W1 ; h1 = elu(agg(P)) -> Hh/Hl
    {
        dim3 grid((HID + BN - 1) / BN, (N_NODES + BM - 1) / BM);
        sgemm_kernel<<<grid, 256, 0, stream>>>(X, W1, P, N_NODES, HID, DIN);
    }
    agg1024_kernel<<<N_NODES, 256, 0, stream>>>((const float4*)P, nullptr, offs, csr_src, csr_w,
                                                Hh, Hl);

    // 3. layer 2 (split-bf16 MFMA): P = h1@W2 ; R = h1@S2 ; h2 = elu(agg(P)+R) -> Hh/Hl
    {
        dim3 grid((HID + GBN - 1) / GBN, (N_NODES + GBM - 1) / GBM);
        mfma_gemm_kernel<<<grid, 256, 0, stream>>>(Hh, Hl, W2h, W2l, P, N_NODES, HID, HID);
        mfma_gemm_kernel<<<grid, 256, 0, stream>>>(Hh, Hl, S2h, S2l, R, N_NODES, HID, HID);
    }
    agg1024_kernel<<<N_NODES, 256, 0, stream>>>((const float4*)P, (const float4*)R, offs, csr_src,
                                                csr_w, Hh, Hl);

    // 4. layer 3 (split-bf16 MFMA): P = h2@W3 ; R = h2@S3 ; out = mean_heads(agg(P)+R)
    {
        dim3 grid((NC3 + GBN - 1) / GBN, (N_NODES + GBM - 1) / GBM);
        mfma_gemm_kernel<<<grid, 256, 0, stream>>>(Hh, Hl, W3h, W3l, P, N_NODES, NC3, HID);
        mfma_gemm_kernel<<<grid, 256, 0, stream>>>(Hh, Hl, S3h, S3l, R, N_NODES, NC3, HID);
    }
    agg3_mean_kernel<<<N_NODES, 128, 0, stream>>>(P, R, offs, csr_src, csr_w, out);
}

// Round 3
// 782.571 us; speedup vs baseline: 3.5582x; 1.6324x over previous
//
#include <hip/hip_runtime.h>
#include <hip/hip_bf16.h>
#include <math.h>

#define N_NODES 20000
#define N_EDGES 320000
#define DIN 50
#define HID 1024
#define NC3 726   // 6*121
#define NCLS 121
#define KCAT 2048

typedef __attribute__((ext_vector_type(8))) short short8;
typedef __attribute__((ext_vector_type(4))) float floatx4;

__device__ __forceinline__ unsigned short f2bf(float v) {
    __hip_bfloat16 h = __float2bfloat16(v);
    return __builtin_bit_cast(unsigned short, h);
}
__device__ __forceinline__ float bf2f(unsigned short u) {
    __hip_bfloat16 h = __builtin_bit_cast(__hip_bfloat16, u);
    return __bfloat162float(h);
}

// ---------------- CSR build ----------------

__global__ void zero_int_kernel(int* p, int n) {
    int i = blockIdx.x * blockDim.x + threadIdx.x;
    if (i < n) p[i] = 0;
}

__global__ void count_deg_kernel(const int* __restrict__ col, int* __restrict__ deg, int e) {
    int i = blockIdx.x * blockDim.x + threadIdx.x;
    if (i < e) atomicAdd(&deg[col[i]], 1);
}

__global__ void compute_dis_kernel(const int* __restrict__ deg, float* __restrict__ dis, int n) {
    int i = blockIdx.x * blockDim.x + threadIdx.x;
    if (i < n) {
        int d = deg[i];
        dis[i] = d > 0 ? rsqrtf((float)d) : 0.0f;
    }
}

__global__ void compute_norm_kernel(const int* __restrict__ row, const int* __restrict__ col,
                                    const float* __restrict__ dis, float* __restrict__ norm, int e) {
    int i = blockIdx.x * blockDim.x + threadIdx.x;
    if (i < e) norm[i] = dis[row[i]] * dis[col[i]];
}

__global__ __launch_bounds__(1024) void scan_kernel(const int* __restrict__ deg,
                                                    int* __restrict__ offs,
                                                    int* __restrict__ cursor,
                                                    int n, int total) {
    __shared__ int part[1024];
    int t = threadIdx.x;
    const int CH = (n + 1023) / 1024;
    int base0 = t * CH;
    int s = 0;
    for (int i = 0; i < CH; ++i) {
        int idx = base0 + i;
        if (idx < n) s += deg[idx];
    }
    part[t] = s;
    __syncthreads();
    for (int d = 1; d < 1024; d <<= 1) {
        int v = (t >= d) ? part[t - d] : 0;
        __syncthreads();
        part[t] += v;
        __syncthreads();
    }
    int run = part[t] - s;
    for (int i = 0; i < CH; ++i) {
        int idx = base0 + i;
        if (idx < n) {
            offs[idx] = run;
            cursor[idx] = run;
            run += deg[idx];
        }
    }
    if (t == 1023) offs[n] = total;
}

__global__ void scatter_kernel(const int* __restrict__ row, const int* __restrict__ col,
                               const float* __restrict__ norm, int* __restrict__ cursor,
                               int* __restrict__ csr_src, float* __restrict__ csr_w, int e) {
    int i = blockIdx.x * blockDim.x + threadIdx.x;
    if (i < e) {
        int c = col[i];
        int pos = atomicAdd(&cursor[c], 1);
        csr_src[pos] = row[i];
        csr_w[pos] = norm[i];
    }
}

// ---------------- weight prep ----------------

// W1 [50][1024] -> padded [64][1024] fp32
__global__ void w1pad_kernel(const float* __restrict__ W1, float* __restrict__ Wp) {
    int i = blockIdx.x * blockDim.x + threadIdx.x;
    if (i >= 64 * HID) return;
    int k = i / HID;
    Wp[i] = (k < DIN) ? W1[i] : 0.0f;
}

// W [1024][1024] fp32 -> Bt hi/lo [1024][2048] bf16 at column offset koff (transposed)
__global__ void convert_wt2_kernel(const float* __restrict__ W,
                                   unsigned short* __restrict__ Th,
                                   unsigned short* __restrict__ Tl, int koff) {
    int i = blockIdx.x * blockDim.x + threadIdx.x;
    if (i >= HID * HID) return;
    int k = i / HID, n = i - k * HID;
    float v = W[i];
    unsigned short h = f2bf(v);
    Th[(size_t)n * KCAT + koff + k] = h;
    Tl[(size_t)n * KCAT + koff + k] = f2bf(v - bf2f(h));
}

// W [1024][726] fp32 -> head-folded transposed Bt hi/lo [121][2048] at column offset koff
__global__ void fold3_kernel(const float* __restrict__ W,
                             unsigned short* __restrict__ Th,
                             unsigned short* __restrict__ Tl, int koff) {
    int i = blockIdx.x * blockDim.x + threadIdx.x;
    if (i >= NCLS * HID) return;
    int c = i / HID, k = i - c * HID;
    const float* r = W + (size_t)k * NC3 + c;
    float v = (r[0] + r[121] + r[242] + r[363] + r[484] + r[605]) * (1.0f / 6.0f);
    unsigned short h = f2bf(v);
    Th[(size_t)c * KCAT + koff + k] = h;
    Tl[(size_t)c * KCAT + koff + k] = f2bf(v - bf2f(h));
}

// ---------------- aggregations ----------------

// gX = A . X  (50-wide fp32, padded to 64)
__global__ __launch_bounds__(64) void aggX_kernel(const float* __restrict__ X,
                                                  const int* __restrict__ offs,
                                                  const int* __restrict__ csr_src,
                                                  const float* __restrict__ csr_w,
                                                  float* __restrict__ gX) {
    int n = blockIdx.x;
    int t = threadIdx.x;
    float a = 0.0f;
    if (t < DIN) {
        int p0 = offs[n], p1 = offs[n + 1];
        for (int p = p0; p < p1; ++p) {
            a = fmaf(csr_w[p], X[(size_t)csr_src[p] * DIN + t], a);
        }
    }
    gX[(size_t)n * 64 + t] = (t < DIN) ? a : 0.0f;
}

// g = A . h  (1024-wide bf16 gather, fp32 accumulate, bf16 hi/lo output)
__global__ __launch_bounds__(256) void agg_bf16_kernel(const unsigned short* __restrict__ h,
                                                       const int* __restrict__ offs,
                                                       const int* __restrict__ csr_src,
                                                       const float* __restrict__ csr_w,
                                                       unsigned short* __restrict__ gh,
                                                       unsigned short* __restrict__ gl) {
    int n = blockIdx.x;
    int t = threadIdx.x;  // 0..255, 4 bf16 each
    float a0 = 0, a1 = 0, a2 = 0, a3 = 0;
    int p0 = offs[n], p1 = offs[n + 1];
    for (int p = p0; p < p1; ++p) {
        int s = csr_src[p];
        float w = csr_w[p];
        ushort4 v = *(const ushort4*)&h[(size_t)s * HID + t * 4];
        a0 = fmaf(w, bf2f(v.x), a0);
        a1 = fmaf(w, bf2f(v.y), a1);
        a2 = fmaf(w, bf2f(v.z), a2);
        a3 = fmaf(w, bf2f(v.w), a3);
    }
    float a[4] = {a0, a1, a2, a3};
    ushort4 hv, lv;
    unsigned short* hp = (unsigned short*)&hv;
    unsigned short* lp = (unsigned short*)&lv;
#pragma unroll
    for (int j = 0; j < 4; ++j) {
        unsigned short hb = f2bf(a[j]);
        hp[j] = hb;
        lp[j] = f2bf(a[j] - bf2f(hb));
    }
    *(ushort4*)&gh[(size_t)n * HID + t * 4] = hv;
    *(ushort4*)&gl[(size_t)n * HID + t * 4] = lv;
}

// ---------------- layer-1 fp32 GEMM, K=64, elu + bf16 hi/lo split epilogue ----------------
#define BM 128
#define BN 128
#define BK 16

__global__ __launch_bounds__(256) void sgemm_l1_kernel(const float* __restrict__ A,   // [M][64]
                                                       const float* __restrict__ B,   // [64][1024]
                                                       unsigned short* __restrict__ Ch,
                                                       unsigned short* __restrict__ Cl,
                                                       int M) {
    const int N = HID, K = 64;
    __shared__ float As[BK][BM + 4];
    __shared__ float Bs[BK][BN + 4];

    const int bm = blockIdx.y * BM;
    const int bn = blockIdx.x * BN;
    const int tid = threadIdx.x;
    const int tm = tid / 16;
    const int tn = tid % 16;

    const int a_r = tid / 4;
    const int a_c = (tid % 4) * 4;
    const int b_r = tid / 32;
    const int b_c = (tid % 32) * 4;

    float acc[8][8];
#pragma unroll
    for (int i = 0; i < 8; ++i)
#pragma unroll
        for (int j = 0; j < 8; ++j) acc[i][j] = 0.0f;

    for (int k0 = 0; k0 < K; k0 += BK) {
#pragma unroll
        for (int half = 0; half < 2; ++half) {
            int r = a_r + half * 64;
            int gm = bm + r;
            float4 v = {0, 0, 0, 0};
            if (gm < M) v = *(const float4*)&A[(size_t)gm * K + k0 + a_c];
            As[a_c + 0][r] = v.x;
            As[a_c + 1][r] = v.y;
            As[a_c + 2][r] = v.z;
            As[a_c + 3][r] = v.w;
        }
#pragma unroll
        for (int half = 0; half < 2; ++half) {
            int r = b_r + half * 8;
            float4 v = *(const float4*)&B[(size_t)(k0 + r) * N + bn + b_c];
            Bs[r][b_c + 0] = v.x;
            Bs[r][b_c + 1] = v.y;
            Bs[r][b_c + 2] = v.z;
            Bs[r][b_c + 3] = v.w;
        }
        __syncthreads();

#pragma unroll
        for (int kk = 0; kk < BK; ++kk) {
            float a[8], b[8];
#pragma unroll
            for (int i = 0; i < 8; ++i) a[i] = As[kk][tm * 8 + i];
#pragma unroll
            for (int j = 0; j < 8; ++j) b[j] = Bs[kk][tn * 8 + j];
#pragma unroll
            for (int i = 0; i < 8; ++i)
#pragma unroll
                for (int j = 0; j < 8; ++j) acc[i][j] = fmaf(a[i], b[j], acc[i][j]);
        }
        __syncthreads();
    }

#pragma unroll
    for (int i = 0; i < 8; ++i) {
        int gm = bm + tm * 8 + i;
        if (gm >= M) continue;
#pragma unroll
        for (int j0 = 0; j0 < 8; j0 += 4) {
            int gn = bn + tn * 8 + j0;
            ushort4 hv, lv;
            unsigned short* hp = (unsigned short*)&hv;
            unsigned short* lp = (unsigned short*)&lv;
#pragma unroll
            for (int jj = 0; jj < 4; ++jj) {
                float v = acc[i][j0 + jj];
                v = v > 0 ? v : expf(v) - 1.0f;  // elu
                unsigned short hb = f2bf(v);
                hp[jj] = hb;
                lp[jj] = f2bf(v - bf2f(hb));
            }
            *(ushort4*)&Ch[(size_t)gm * HID + gn] = hv;
            *(ushort4*)&Cl[(size_t)gm * HID + gn] = lv;
        }
    }
}

// ---------------- split-bf16 MFMA GEMM over concatenated A = [g | h], K = 2048 ----------------
// C = A @ B as Ah@Bh + Al@Bh + Ah@Bl (fp32 accumulate).
// A halves: g (k<1024) and h (k>=1024), each [M][1024] bf16 hi/lo.
// B: Bt hi/lo [N][2048] (transposed).
// EPI 0: elu + bf16 hi/lo split -> Coh/Col (ldc). EPI 1: fp32 -> Coh (ldc).

#define GBM 128
#define GBN 128
#define GBK 32
#define LDK 40

template <int EPI>
__global__ __launch_bounds__(256, 2) void mfma_cat_kernel(
        const unsigned short* __restrict__ Agh, const unsigned short* __restrict__ Agl,
        const unsigned short* __restrict__ Ahh, const unsigned short* __restrict__ Ahl,
        const unsigned short* __restrict__ Bth, const unsigned short* __restrict__ Btl,
        void* __restrict__ Coh, void* __restrict__ Col,
        int M, int N, int ldc) {
    __shared__ __align__(16) unsigned short sAh[GBM][LDK];
    __shared__ __align__(16) unsigned short sAl[GBM][LDK];
    __shared__ __align__(16) unsigned short sBh[GBN][LDK];
    __shared__ __align__(16) unsigned short sBl[GBN][LDK];

    const int tid = threadIdx.x;
    const int lane = tid & 63;
    const int wave = tid >> 6;
    const int wm = wave >> 1;
    const int wn = wave & 1;
    const int bm = blockIdx.y * GBM;
    const int bn = blockIdx.x * GBN;

    const int st_r = tid >> 2;
    const int st_kc = (tid & 3) * 8;

    const int frow = lane & 15;
    const int fkc = (lane >> 4) * 8;

    floatx4 acc[4][4];
#pragma unroll
    for (int i = 0; i < 4; ++i)
#pragma unroll
        for (int j = 0; j < 4; ++j) acc[i][j] = (floatx4){0.f, 0.f, 0.f, 0.f};

    uint4 rah[2], ral[2], rbh[2], rbl[2];

    auto prefetch = [&](int k0) {
        const unsigned short* ah = (k0 < HID) ? Agh : Ahh;
        const unsigned short* al = (k0 < HID) ? Agl : Ahl;
        int kc = (k0 & (HID - 1)) + st_kc;
#pragma unroll
        for (int p = 0; p < 2; ++p) {
            int gm = bm + st_r + p * 64;
            bool ap = gm < M;
            size_t ao = (size_t)gm * HID + kc;
            rah[p] = ap ? *(const uint4*)&ah[ao] : (uint4){0, 0, 0, 0};
            ral[p] = ap ? *(const uint4*)&al[ao] : (uint4){0, 0, 0, 0};
            int gn = bn + st_r + p * 64;
            bool bp = gn < N;
            size_t bo = (size_t)gn * KCAT + k0 + st_kc;
            rbh[p] = bp ? *(const uint4*)&Bth[bo] : (uint4){0, 0, 0, 0};
            rbl[p] = bp ? *(const uint4*)&Btl[bo] : (uint4){0, 0, 0, 0};
        }
    };

    prefetch(0);

    for (int k0 = 0; k0 < KCAT; k0 += GBK) {
        __syncthreads();
#pragma unroll
        for (int p = 0; p < 2; ++p) {
            int r = st_r + p * 64;
            *(uint4*)&sAh[r][st_kc] = rah[p];
            *(uint4*)&sAl[r][st_kc] = ral[p];
            *(uint4*)&sBh[r][st_kc] = rbh[p];
            *(uint4*)&sBl[r][st_kc] = rbl[p];
        }
        __syncthreads();

        int kn = k0 + GBK;
        if (kn < KCAT) prefetch(kn);

        short8 fah[4], fal[4], fbh[4], fbl[4];
#pragma unroll
        for (int i = 0; i < 4; ++i) {
            int r = wm * 64 + i * 16 + frow;
            fah[i] = *(const short8*)&sAh[r][fkc];
            fal[i] = *(const short8*)&sAl[r][fkc];
        }
#pragma unroll
        for (int j = 0; j < 4; ++j) {
            int r = wn * 64 + j * 16 + frow;
            fbh[j] = *(const short8*)&sBh[r][fkc];
            fbl[j] = *(const short8*)&sBl[r][fkc];
        }
#pragma unroll
        for (int i = 0; i < 4; ++i)
#pragma unroll
            for (int j = 0; j < 4; ++j) {
                acc[i][j] = __builtin_amdgcn_mfma_f32_16x16x32_bf16(fah[i], fbh[j], acc[i][j], 0, 0, 0);
                acc[i][j] = __builtin_amdgcn_mfma_f32_16x16x32_bf16(fal[i], fbh[j], acc[i][j], 0, 0, 0);
                acc[i][j] = __builtin_amdgcn_mfma_f32_16x16x32_bf16(fah[i], fbl[j], acc[i][j], 0, 0, 0);
            }
    }

    // C/D layout: col=lane&15, row=(lane>>4)*4+reg
    const int c_r0 = (lane >> 4) * 4;
    const int c_c = lane & 15;
#pragma unroll
    for (int i = 0; i < 4; ++i)
#pragma unroll
        for (int j = 0; j < 4; ++j) {
            int gn = bn + wn * 64 + j * 16 + c_c;
            if (gn >= N) continue;
#pragma unroll
            for (int r = 0; r < 4; ++r) {
                int gm = bm + wm * 64 + i * 16 + c_r0 + r;
                if (gm >= M) continue;
                float v = acc[i][j][r];
                if (EPI == 0) {
                    v = v > 0 ? v : expf(v) - 1.0f;  // elu
                    unsigned short hb = f2bf(v);
                    ((unsigned short*)Coh)[(size_t)gm * ldc + gn] = hb;
                    ((unsigned short*)Col)[(size_t)gm * ldc + gn] = f2bf(v - bf2f(hb));
                } else {
                    ((float*)Coh)[(size_t)gm * ldc + gn] = v;
                }
            }
        }
}

// ---------------- launch ----------------

static inline size_t align_up(size_t x, size_t a) { return (x + a - 1) & ~(a - 1); }

extern "C" void kernel_launch(void* const* d_in, const int* in_sizes, int n_in,
                              void* d_out, int out_size, void* d_ws, size_t ws_size,
                              hipStream_t stream) {
    const float* X  = (const float*)d_in[0];
    const int* erow = (const int*)d_in[1];
    const int* ecol = (const int*)d_in[1] + N_EDGES;
    const float* W1 = (const float*)d_in[2];
    const float* W2 = (const float*)d_in[3];
    const float* S2 = (const float*)d_in[4];
    const float* W3 = (const float*)d_in[5];
    const float* S3 = (const float*)d_in[6];
    float* out = (float*)d_out;

    // workspace carve-up
    char* w = (char*)d_ws;
    int* deg     = (int*)w;             w += align_up((size_t)N_NODES * 4, 256);
    int* offs    = (int*)w;             w += align_up((size_t)(N_NODES + 1) * 4, 256);
    int* cursor  = (int*)w;             w += align_up((size_t)N_NODES * 4, 256);
    int* csr_src = (int*)w;             w += align_up((size_t)N_EDGES * 4, 256);
    float* dis   = (float*)w;           w += align_up((size_t)N_NODES * 4, 256);
    float* norm  = (float*)w;           w += align_up((size_t)N_EDGES * 4, 256);
    float* csr_w = (float*)w;           w += align_up((size_t)N_EDGES * 4, 256);
    float* gX    = (float*)w;           w += align_up((size_t)N_NODES * 64 * 4, 256);
    float* W1p   = (float*)w;           w += align_up((size_t)64 * HID * 4, 256);
    unsigned short* h1h = (unsigned short*)w; w += align_up((size_t)N_NODES * HID * 2, 256);
    unsigned short* h1l = (unsigned short*)w; w += align_up((size_t)N_NODES * HID * 2, 256);
    unsigned short* gh  = (unsigned short*)w; w += align_up((size_t)N_NODES * HID * 2, 256);
    unsigned short* gl  = (unsigned short*)w; w += align_up((size_t)N_NODES * HID * 2, 256);
    unsigned short* h2h = (unsigned short*)w; w += align_up((size_t)N_NODES * HID * 2, 256);
    unsigned short* h2l = (unsigned short*)w; w += align_up((size_t)N_NODES * HID * 2, 256);
    unsigned short* Bt2h = (unsigned short*)w; w += align_up((size_t)HID * KCAT * 2, 256);
    unsigned short* Bt2l = (unsigned short*)w; w += align_up((size_t)HID * KCAT * 2, 256);
    unsigned short* Bt3h = (unsigned short*)w; w += align_up((size_t)NCLS * KCAT * 2, 256);
    unsigned short* Bt3l = (unsigned short*)w; w += align_up((size_t)NCLS * KCAT * 2, 256);

    const int TB = 256;
    int nb_n = (N_NODES + TB - 1) / TB;
    int nb_e = (N_EDGES + TB - 1) / TB;

    // 1. degree / norm / CSR build
    zero_int_kernel<<<nb_n, TB, 0, stream>>>(deg, N_NODES);
    count_deg_kernel<<<nb_e, TB, 0, stream>>>(ecol, deg, N_EDGES);
    compute_dis_kernel<<<nb_n, TB, 0, stream>>>(deg, dis, N_NODES);
    compute_norm_kernel<<<nb_e, TB, 0, stream>>>(erow, ecol, dis, norm, N_EDGES);
    scan_kernel<<<1, 1024, 0, stream>>>(deg, offs, cursor, N_NODES, N_EDGES);
    scatter_kernel<<<nb_e, TB, 0, stream>>>(erow, ecol, norm, cursor, csr_src, csr_w, N_EDGES);

    // 2. weight prep
    w1pad_kernel<<<(64 * HID + 255) / 256, 256, 0, stream>>>(W1, W1p);
    convert_wt2_kernel<<<(HID * HID + 255) / 256, 256, 0, stream>>>(W2, Bt2h, Bt2l, 0);
    convert_wt2_kernel<<<(HID * HID + 255) / 256, 256, 0, stream>>>(S2, Bt2h, Bt2l, HID);
    fold3_kernel<<<(NCLS * HID + 255) / 256, 256, 0, stream>>>(W3, Bt3h, Bt3l, 0);
    fold3_kernel<<<(NCLS * HID + 255) / 256, 256, 0, stream>>>(S3, Bt3h, Bt3l, HID);

    // 3. layer 1: gX = A.X ; h1 = elu(gX @ W1) -> bf16 hi/lo
    aggX_kernel<<<N_NODES, 64, 0, stream>>>(X, offs, csr_src, csr_w, gX);
    {
        dim3 grid(HID / BN, (N_NODES + BM - 1) / BM);
        sgemm_l1_kernel<<<grid, 256, 0, stream>>>(gX, W1p, h1h, h1l, N_NODES);
    }

    // 4. layer 2: g1 = A.h1 ; h2 = elu([g1|h1] @ [W2;S2]) -> bf16 hi/lo
    agg_bf16_kernel<<<N_NODES, 256, 0, stream>>>(h1h, offs, csr_src, csr_w, gh, gl);
    {
        dim3 grid(HID / GBN, (N_NODES + GBM - 1) / GBM);
        mfma_cat_kernel<0><<<grid, 256, 0, stream>>>(gh, gl, h1h, h1l, Bt2h, Bt2l,
                                                     h2h, h2l, N_NODES, HID, HID);
    }

    // 5. layer 3: g2 = A.h2 ; out = [g2|h2] @ [W3bar;S3bar]  (head-mean folded into weights)
    agg_bf16_kernel<<<N_NODES, 256, 0, stream>>>(h2h, offs, csr_src, csr_w, gh, gl);
    {
        dim3 grid(1, (N_NODES + GBM - 1) / GBM);
        mfma_cat_kernel<1><<<grid, 256, 0, stream>>>(gh, gl, h2h, h2l, Bt3h, Bt3l,
                                                     out, nullptr, N_NODES, NCLS, NCLS);
    }
}

// Round 4
// 594.710 us; speedup vs baseline: 4.6822x; 1.3159x over previous
//
#include <hip/hip_runtime.h>
#include <hip/hip_bf16.h>
#include <math.h>

#define N_NODES 20000
#define N_EDGES 320000
#define DIN 50
#define HID 1024
#define NC3 726   // 6*121
#define NCLS 121
#define KCAT 2048

typedef __attribute__((ext_vector_type(8))) _Float16 half8;
typedef __attribute__((ext_vector_type(4))) float floatx4;

__device__ __forceinline__ unsigned short f2h(float v) {
    _Float16 h = (_Float16)v;
    return __builtin_bit_cast(unsigned short, h);
}
__device__ __forceinline__ float h2f(unsigned short u) {
    return (float)__builtin_bit_cast(_Float16, u);
}

// ---------------- CSR build ----------------

__global__ void zero_int_kernel(int* p, int n) {
    int i = blockIdx.x * blockDim.x + threadIdx.x;
    if (i < n) p[i] = 0;
}

__global__ void count_deg_kernel(const int* __restrict__ col, int* __restrict__ deg, int e) {
    int i = blockIdx.x * blockDim.x + threadIdx.x;
    if (i < e) atomicAdd(&deg[col[i]], 1);
}

__global__ void compute_dis_kernel(const int* __restrict__ deg, float* __restrict__ dis, int n) {
    int i = blockIdx.x * blockDim.x + threadIdx.x;
    if (i < n) {
        int d = deg[i];
        dis[i] = d > 0 ? rsqrtf((float)d) : 0.0f;
    }
}

__global__ void compute_norm_kernel(const int* __restrict__ row, const int* __restrict__ col,
                                    const float* __restrict__ dis, float* __restrict__ norm, int e) {
    int i = blockIdx.x * blockDim.x + threadIdx.x;
    if (i < e) norm[i] = dis[row[i]] * dis[col[i]];
}

__global__ __launch_bounds__(1024) void scan_kernel(const int* __restrict__ deg,
                                                    int* __restrict__ offs,
                                                    int* __restrict__ cursor,
                                                    int n, int total) {
    __shared__ int part[1024];
    int t = threadIdx.x;
    const int CH = (n + 1023) / 1024;
    int base0 = t * CH;
    int s = 0;
    for (int i = 0; i < CH; ++i) {
        int idx = base0 + i;
        if (idx < n) s += deg[idx];
    }
    part[t] = s;
    __syncthreads();
    for (int d = 1; d < 1024; d <<= 1) {
        int v = (t >= d) ? part[t - d] : 0;
        __syncthreads();
        part[t] += v;
        __syncthreads();
    }
    int run = part[t] - s;
    for (int i = 0; i < CH; ++i) {
        int idx = base0 + i;
        if (idx < n) {
            offs[idx] = run;
            cursor[idx] = run;
            run += deg[idx];
        }
    }
    if (t == 1023) offs[n] = total;
}

__global__ void scatter_kernel(const int* __restrict__ row, const int* __restrict__ col,
                               const float* __restrict__ norm, int* __restrict__ cursor,
                               int* __restrict__ csr_src, float* __restrict__ csr_w, int e) {
    int i = blockIdx.x * blockDim.x + threadIdx.x;
    if (i < e) {
        int c = col[i];
        int pos = atomicAdd(&cursor[c], 1);
        csr_src[pos] = row[i];
        csr_w[pos] = norm[i];
    }
}

// ---------------- weight prep ----------------

// W1 [50][1024] -> padded [64][1024] fp32
__global__ void w1pad_kernel(const float* __restrict__ W1, float* __restrict__ Wp) {
    int i = blockIdx.x * blockDim.x + threadIdx.x;
    if (i >= 64 * HID) return;
    int k = i / HID;
    Wp[i] = (k < DIN) ? W1[i] : 0.0f;
}

// W [1024][1024] fp32 -> Bt fp16 [1024][2048] at column offset koff (transposed)
__global__ void convert_wt2_kernel(const float* __restrict__ W,
                                   unsigned short* __restrict__ Th, int koff) {
    int i = blockIdx.x * blockDim.x + threadIdx.x;
    if (i >= HID * HID) return;
    int k = i / HID, n = i - k * HID;
    Th[(size_t)n * KCAT + koff + k] = f2h(W[i]);
}

// W [1024][726] fp32 -> head-folded transposed Bt fp16 [121][2048] at column offset koff
__global__ void fold3_kernel(const float* __restrict__ W,
                             unsigned short* __restrict__ Th, int koff) {
    int i = blockIdx.x * blockDim.x + threadIdx.x;
    if (i >= NCLS * HID) return;
    int c = i / HID, k = i - c * HID;
    const float* r = W + (size_t)k * NC3 + c;
    float v = (r[0] + r[121] + r[242] + r[363] + r[484] + r[605]) * (1.0f / 6.0f);
    Th[(size_t)c * KCAT + koff + k] = f2h(v);
}

// ---------------- aggregations ----------------

// gX = A . X  (50-wide fp32, padded to 64)
__global__ __launch_bounds__(64) void aggX_kernel(const float* __restrict__ X,
                                                  const int* __restrict__ offs,
                                                  const int* __restrict__ csr_src,
                                                  const float* __restrict__ csr_w,
                                                  float* __restrict__ gX) {
    int n = blockIdx.x;
    int t = threadIdx.x;
    float a = 0.0f;
    if (t < DIN) {
        int p0 = offs[n], p1 = offs[n + 1];
        for (int p = p0; p < p1; ++p) {
            a = fmaf(csr_w[p], X[(size_t)csr_src[p] * DIN + t], a);
        }
    }
    gX[(size_t)n * 64 + t] = (t < DIN) ? a : 0.0f;
}

// g = A . h  (1024-wide fp16 gather, fp32 accumulate, fp16 output)
__global__ __launch_bounds__(256) void agg_f16_kernel(const unsigned short* __restrict__ h,
                                                      const int* __restrict__ offs,
                                                      const int* __restrict__ csr_src,
                                                      const float* __restrict__ csr_w,
                                                      unsigned short* __restrict__ g) {
    int n = blockIdx.x;
    int t = threadIdx.x;  // 0..255, 4 fp16 each
    float a0 = 0, a1 = 0, a2 = 0, a3 = 0;
    int p0 = offs[n], p1 = offs[n + 1];
    for (int p = p0; p < p1; ++p) {
        int s = csr_src[p];
        float w = csr_w[p];
        ushort4 v = *(const ushort4*)&h[(size_t)s * HID + t * 4];
        a0 = fmaf(w, h2f(v.x), a0);
        a1 = fmaf(w, h2f(v.y), a1);
        a2 = fmaf(w, h2f(v.z), a2);
        a3 = fmaf(w, h2f(v.w), a3);
    }
    ushort4 ov;
    ov.x = f2h(a0); ov.y = f2h(a1); ov.z = f2h(a2); ov.w = f2h(a3);
    *(ushort4*)&g[(size_t)n * HID + t * 4] = ov;
}

// ---------------- layer-1 fp32 GEMM, K=64, elu + fp16 epilogue ----------------
#define BM 128
#define BN 128
#define BK 16

__global__ __launch_bounds__(256) void sgemm_l1_kernel(const float* __restrict__ A,   // [M][64]
                                                       const float* __restrict__ B,   // [64][1024]
                                                       unsigned short* __restrict__ Ch,
                                                       int M) {
    const int N = HID, K = 64;
    __shared__ float As[BK][BM + 4];
    __shared__ float Bs[BK][BN + 4];

    const int bm = blockIdx.y * BM;
    const int bn = blockIdx.x * BN;
    const int tid = threadIdx.x;
    const int tm = tid / 16;
    const int tn = tid % 16;

    const int a_r = tid / 4;
    const int a_c = (tid % 4) * 4;
    const int b_r = tid / 32;
    const int b_c = (tid % 32) * 4;

    float acc[8][8];
#pragma unroll
    for (int i = 0; i < 8; ++i)
#pragma unroll
        for (int j = 0; j < 8; ++j) acc[i][j] = 0.0f;

    for (int k0 = 0; k0 < K; k0 += BK) {
#pragma unroll
        for (int half = 0; half < 2; ++half) {
            int r = a_r + half * 64;
            int gm = bm + r;
            float4 v = {0, 0, 0, 0};
            if (gm < M) v = *(const float4*)&A[(size_t)gm * K + k0 + a_c];
            As[a_c + 0][r] = v.x;
            As[a_c + 1][r] = v.y;
            As[a_c + 2][r] = v.z;
            As[a_c + 3][r] = v.w;
        }
#pragma unroll
        for (int half = 0; half < 2; ++half) {
            int r = b_r + half * 8;
            float4 v = *(const float4*)&B[(size_t)(k0 + r) * N + bn + b_c];
            Bs[r][b_c + 0] = v.x;
            Bs[r][b_c + 1] = v.y;
            Bs[r][b_c + 2] = v.z;
            Bs[r][b_c + 3] = v.w;
        }
        __syncthreads();

#pragma unroll
        for (int kk = 0; kk < BK; ++kk) {
            float a[8], b[8];
#pragma unroll
            for (int i = 0; i < 8; ++i) a[i] = As[kk][tm * 8 + i];
#pragma unroll
            for (int j = 0; j < 8; ++j) b[j] = Bs[kk][tn * 8 + j];
#pragma unroll
            for (int i = 0; i < 8; ++i)
#pragma unroll
                for (int j = 0; j < 8; ++j) acc[i][j] = fmaf(a[i], b[j], acc[i][j]);
        }
        __syncthreads();
    }

#pragma unroll
    for (int i = 0; i < 8; ++i) {
        int gm = bm + tm * 8 + i;
        if (gm >= M) continue;
#pragma unroll
        for (int j0 = 0; j0 < 8; j0 += 4) {
            int gn = bn + tn * 8 + j0;
            ushort4 hv;
            unsigned short* hp = (unsigned short*)&hv;
#pragma unroll
            for (int jj = 0; jj < 4; ++jj) {
                float v = acc[i][j0 + jj];
                v = v > 0 ? v : expf(v) - 1.0f;  // elu
                hp[jj] = f2h(v);
            }
            *(ushort4*)&Ch[(size_t)gm * HID + gn] = hv;
        }
    }
}

// ---------------- fp16 MFMA GEMM over concatenated A = [g | h], K = 2048 ----------------
// A halves: g (k<1024) and h (k>=1024), each [M][1024] fp16.
// B: Bt fp16 [N][2048] (transposed).
// EPI 0: elu -> fp16 Co (ldc). EPI 1: fp32 -> Co (ldc).

#define GBM 128
#define GBN 128
#define GBK 32
#define LDK 40

template <int EPI>
__global__ __launch_bounds__(256, 3) void mfma_cat_kernel(
        const unsigned short* __restrict__ Ag, const unsigned short* __restrict__ Ah,
        const unsigned short* __restrict__ Bt,
        void* __restrict__ Co,
        int M, int N, int ldc) {
    __shared__ __align__(16) unsigned short sA[GBM][LDK];
    __shared__ __align__(16) unsigned short sB[GBN][LDK];

    const int tid = threadIdx.x;
    const int lane = tid & 63;
    const int wave = tid >> 6;
    const int wm = wave >> 1;
    const int wn = wave & 1;
    const int bm = blockIdx.y * GBM;
    const int bn = blockIdx.x * GBN;

    const int st_r = tid >> 2;
    const int st_kc = (tid & 3) * 8;

    const int frow = lane & 15;
    const int fkc = (lane >> 4) * 8;

    floatx4 acc[4][4];
#pragma unroll
    for (int i = 0; i < 4; ++i)
#pragma unroll
        for (int j = 0; j < 4; ++j) acc[i][j] = (floatx4){0.f, 0.f, 0.f, 0.f};

    uint4 ra[2], rb[2];

    auto prefetch = [&](int k0) {
        const unsigned short* ap = (k0 < HID) ? Ag : Ah;
        int kc = (k0 & (HID - 1)) + st_kc;
#pragma unroll
        for (int p = 0; p < 2; ++p) {
            int gm = bm + st_r + p * 64;
            bool apred = gm < M;
            ra[p] = apred ? *(const uint4*)&ap[(size_t)gm * HID + kc] : (uint4){0, 0, 0, 0};
            int gn = bn + st_r + p * 64;
            bool bpred = gn < N;
            rb[p] = bpred ? *(const uint4*)&Bt[(size_t)gn * KCAT + k0 + st_kc] : (uint4){0, 0, 0, 0};
        }
    };

    prefetch(0);

    for (int k0 = 0; k0 < KCAT; k0 += GBK) {
        __syncthreads();
#pragma unroll
        for (int p = 0; p < 2; ++p) {
            int r = st_r + p * 64;
            *(uint4*)&sA[r][st_kc] = ra[p];
            *(uint4*)&sB[r][st_kc] = rb[p];
        }
        __syncthreads();

        int kn = k0 + GBK;
        if (kn < KCAT) prefetch(kn);

        half8 fa[4], fb[4];
#pragma unroll
        for (int i = 0; i < 4; ++i) {
            int r = wm * 64 + i * 16 + frow;
            fa[i] = *(const half8*)&sA[r][fkc];
        }
#pragma unroll
        for (int j = 0; j < 4; ++j) {
            int r = wn * 64 + j * 16 + frow;
            fb[j] = *(const half8*)&sB[r][fkc];
        }
#pragma unroll
        for (int i = 0; i < 4; ++i)
#pragma unroll
            for (int j = 0; j < 4; ++j)
                acc[i][j] = __builtin_amdgcn_mfma_f32_16x16x32_f16(fa[i], fb[j], acc[i][j], 0, 0, 0);
    }

    // C/D layout: col=lane&15, row=(lane>>4)*4+reg
    const int c_r0 = (lane >> 4) * 4;
    const int c_c = lane & 15;
#pragma unroll
    for (int i = 0; i < 4; ++i)
#pragma unroll
        for (int j = 0; j < 4; ++j) {
            int gn = bn + wn * 64 + j * 16 + c_c;
            if (gn >= N) continue;
#pragma unroll
            for (int r = 0; r < 4; ++r) {
                int gm = bm + wm * 64 + i * 16 + c_r0 + r;
                if (gm >= M) continue;
                float v = acc[i][j][r];
                if (EPI == 0) {
                    v = v > 0 ? v : expf(v) - 1.0f;  // elu
                    ((unsigned short*)Co)[(size_t)gm * ldc + gn] = f2h(v);
                } else {
                    ((float*)Co)[(size_t)gm * ldc + gn] = v;
                }
            }
        }
}

// ---------------- launch ----------------

static inline size_t align_up(size_t x, size_t a) { return (x + a - 1) & ~(a - 1); }

extern "C" void kernel_launch(void* const* d_in, const int* in_sizes, int n_in,
                              void* d_out, int out_size, void* d_ws, size_t ws_size,
                              hipStream_t stream) {
    const float* X  = (const float*)d_in[0];
    const int* erow = (const int*)d_in[1];
    const int* ecol = (const int*)d_in[1] + N_EDGES;
    const float* W1 = (const float*)d_in[2];
    const float* W2 = (const float*)d_in[3];
    const float* S2 = (const float*)d_in[4];
    const float* W3 = (const float*)d_in[5];
    const float* S3 = (const float*)d_in[6];
    float* out = (float*)d_out;

    // workspace carve-up
    char* w = (char*)d_ws;
    int* deg     = (int*)w;             w += align_up((size_t)N_NODES * 4, 256);
    int* offs    = (int*)w;             w += align_up((size_t)(N_NODES + 1) * 4, 256);
    int* cursor  = (int*)w;             w += align_up((size_t)N_NODES * 4, 256);
    int* csr_src = (int*)w;             w += align_up((size_t)N_EDGES * 4, 256);
    float* dis   = (float*)w;           w += align_up((size_t)N_NODES * 4, 256);
    float* norm  = (float*)w;           w += align_up((size_t)N_EDGES * 4, 256);
    float* csr_w = (float*)w;           w += align_up((size_t)N_EDGES * 4, 256);
    float* gX    = (float*)w;           w += align_up((size_t)N_NODES * 64 * 4, 256);
    float* W1p   = (float*)w;           w += align_up((size_t)64 * HID * 4, 256);
    unsigned short* h1 = (unsigned short*)w;  w += align_up((size_t)N_NODES * HID * 2, 256);
    unsigned short* g  = (unsigned short*)w;  w += align_up((size_t)N_NODES * HID * 2, 256);
    unsigned short* h2 = (unsigned short*)w;  w += align_up((size_t)N_NODES * HID * 2, 256);
    unsigned short* Bt2 = (unsigned short*)w; w += align_up((size_t)HID * KCAT * 2, 256);
    unsigned short* Bt3 = (unsigned short*)w; w += align_up((size_t)NCLS * KCAT * 2, 256);

    const int TB = 256;
    int nb_n = (N_NODES + TB - 1) / TB;
    int nb_e = (N_EDGES + TB - 1) / TB;

    // 1. degree / norm / CSR build
    zero_int_kernel<<<nb_n, TB, 0, stream>>>(deg, N_NODES);
    count_deg_kernel<<<nb_e, TB, 0, stream>>>(ecol, deg, N_EDGES);
    compute_dis_kernel<<<nb_n, TB, 0, stream>>>(deg, dis, N_NODES);
    compute_norm_kernel<<<nb_e, TB, 0, stream>>>(erow, ecol, dis, norm, N_EDGES);
    scan_kernel<<<1, 1024, 0, stream>>>(deg, offs, cursor, N_NODES, N_EDGES);
    scatter_kernel<<<nb_e, TB, 0, stream>>>(erow, ecol, norm, cursor, csr_src, csr_w, N_EDGES);

    // 2. weight prep (fp16)
    w1pad_kernel<<<(64 * HID + 255) / 256, 256, 0, stream>>>(W1, W1p);
    convert_wt2_kernel<<<(HID * HID + 255) / 256, 256, 0, stream>>>(W2, Bt2, 0);
    convert_wt2_kernel<<<(HID * HID + 255) / 256, 256, 0, stream>>>(S2, Bt2, HID);
    fold3_kernel<<<(NCLS * HID + 255) / 256, 256, 0, stream>>>(W3, Bt3, 0);
    fold3_kernel<<<(NCLS * HID + 255) / 256, 256, 0, stream>>>(S3, Bt3, HID);

    // 3. layer 1: gX = A.X ; h1 = elu(gX @ W1) -> fp16
    aggX_kernel<<<N_NODES, 64, 0, stream>>>(X, offs, csr_src, csr_w, gX);
    {
        dim3 grid(HID / BN, (N_NODES + BM - 1) / BM);
        sgemm_l1_kernel<<<grid, 256, 0, stream>>>(gX, W1p, h1, N_NODES);
    }

    // 4. layer 2: g1 = A.h1 ; h2 = elu([g1|h1] @ [W2;S2]) -> fp16
    agg_f16_kernel<<<N_NODES, 256, 0, stream>>>(h1, offs, csr_src, csr_w, g);
    {
        dim3 grid(HID / GBN, (N_NODES + GBM - 1) / GBM);
        mfma_cat_kernel<0><<<grid, 256, 0, stream>>>(g, h1, Bt2, h2, N_NODES, HID, HID);
    }

    // 5. layer 3: g2 = A.h2 ; out = [g2|h2] @ [W3bar;S3bar]  (head-mean folded into weights)
    agg_f16_kernel<<<N_NODES, 256, 0, stream>>>(h2, offs, csr_src, csr_w, g);
    {
        dim3 grid(1, (N_NODES + GBM - 1) / GBM);
        mfma_cat_kernel<1><<<grid, 256, 0, stream>>>(g, h2, Bt3, out, N_NODES, NCLS, NCLS);
    }
}

// Round 5
// 585.906 us; speedup vs baseline: 4.7526x; 1.0150x over previous
//
#include <hip/hip_runtime.h>
#include <hip/hip_bf16.h>
#include <math.h>

#define N_NODES 20000
#define N_EDGES 320000
#define DIN 50
#define HID 1024
#define NC3 726   // 6*121
#define NCLS 121
#define KCAT 2048

typedef __attribute__((ext_vector_type(8))) _Float16 half8;
typedef __attribute__((ext_vector_type(4))) float floatx4;

__device__ __forceinline__ unsigned short f2h(float v) {
    _Float16 h = (_Float16)v;
    return __builtin_bit_cast(unsigned short, h);
}
__device__ __forceinline__ float h2f(unsigned short u) {
    return (float)__builtin_bit_cast(_Float16, u);
}

// async global->LDS, 16B per lane. LDS dest must equal wave-uniform base + lane*16.
__device__ __forceinline__ void async16(const void* g, void* l) {
    __builtin_amdgcn_global_load_lds(
        (const __attribute__((address_space(1))) void*)g,
        (__attribute__((address_space(3))) void*)l,
        16, 0, 0);
}

// ---------------- CSR build ----------------

__global__ void zero_int_kernel(int* p, int n) {
    int i = blockIdx.x * blockDim.x + threadIdx.x;
    if (i < n) p[i] = 0;
}

__global__ void count_deg_kernel(const int* __restrict__ col, int* __restrict__ deg, int e) {
    int i = blockIdx.x * blockDim.x + threadIdx.x;
    if (i < e) atomicAdd(&deg[col[i]], 1);
}

__global__ void compute_dis_kernel(const int* __restrict__ deg, float* __restrict__ dis, int n) {
    int i = blockIdx.x * blockDim.x + threadIdx.x;
    if (i < n) {
        int d = deg[i];
        dis[i] = d > 0 ? rsqrtf((float)d) : 0.0f;
    }
}

__global__ void compute_norm_kernel(const int* __restrict__ row, const int* __restrict__ col,
                                    const float* __restrict__ dis, float* __restrict__ norm, int e) {
    int i = blockIdx.x * blockDim.x + threadIdx.x;
    if (i < e) norm[i] = dis[row[i]] * dis[col[i]];
}

__global__ __launch_bounds__(1024) void scan_kernel(const int* __restrict__ deg,
                                                    int* __restrict__ offs,
                                                    int* __restrict__ cursor,
                                                    int n, int total) {
    __shared__ int part[1024];
    int t = threadIdx.x;
    const int CH = (n + 1023) / 1024;
    int base0 = t * CH;
    int s = 0;
    for (int i = 0; i < CH; ++i) {
        int idx = base0 + i;
        if (idx < n) s += deg[idx];
    }
    part[t] = s;
    __syncthreads();
    for (int d = 1; d < 1024; d <<= 1) {
        int v = (t >= d) ? part[t - d] : 0;
        __syncthreads();
        part[t] += v;
        __syncthreads();
    }
    int run = part[t] - s;
    for (int i = 0; i < CH; ++i) {
        int idx = base0 + i;
        if (idx < n) {
            offs[idx] = run;
            cursor[idx] = run;
            run += deg[idx];
        }
    }
    if (t == 1023) offs[n] = total;
}

__global__ void scatter_kernel(const int* __restrict__ row, const int* __restrict__ col,
                               const float* __restrict__ norm, int* __restrict__ cursor,
                               int* __restrict__ csr_src, float* __restrict__ csr_w, int e) {
    int i = blockIdx.x * blockDim.x + threadIdx.x;
    if (i < e) {
        int c = col[i];
        int pos = atomicAdd(&cursor[c], 1);
        csr_src[pos] = row[i];
        csr_w[pos] = norm[i];
    }
}

// ---------------- weight prep ----------------

// W1 [50][1024] fp32 -> Bt1 fp16 [1024][64] (transposed, K padded to 64)
__global__ void w1t_kernel(const float* __restrict__ W1, unsigned short* __restrict__ Bt1) {
    int i = blockIdx.x * blockDim.x + threadIdx.x;
    if (i >= HID * 64) return;
    int n = i / 64, k = i - n * 64;
    Bt1[i] = (k < DIN) ? f2h(W1[(size_t)k * HID + n]) : (unsigned short)0;
}

// W [1024][1024] fp32 -> Bt fp16 [1024][2048] at column offset koff (transposed)
__global__ void convert_wt2_kernel(const float* __restrict__ W,
                                   unsigned short* __restrict__ Th, int koff) {
    int i = blockIdx.x * blockDim.x + threadIdx.x;
    if (i >= HID * HID) return;
    int k = i / HID, n = i - k * HID;
    Th[(size_t)n * KCAT + koff + k] = f2h(W[i]);
}

// W [1024][726] fp32 -> head-folded transposed Bt fp16 [121][2048] at column offset koff
__global__ void fold3_kernel(const float* __restrict__ W,
                             unsigned short* __restrict__ Th, int koff) {
    int i = blockIdx.x * blockDim.x + threadIdx.x;
    if (i >= NCLS * HID) return;
    int c = i / HID, k = i - c * HID;
    const float* r = W + (size_t)k * NC3 + c;
    float v = (r[0] + r[121] + r[242] + r[363] + r[484] + r[605]) * (1.0f / 6.0f);
    Th[(size_t)c * KCAT + koff + k] = f2h(v);
}

// ---------------- aggregations ----------------

// gX = A . X  (50-wide fp32 gather -> fp16 out, rows padded to 64)
__global__ __launch_bounds__(64) void aggX_kernel(const float* __restrict__ X,
                                                  const int* __restrict__ offs,
                                                  const int* __restrict__ csr_src,
                                                  const float* __restrict__ csr_w,
                                                  unsigned short* __restrict__ gX) {
    int n = blockIdx.x;
    int t = threadIdx.x;
    float a = 0.0f;
    if (t < DIN) {
        int p0 = offs[n], p1 = offs[n + 1];
        for (int p = p0; p < p1; ++p) {
            a = fmaf(csr_w[p], X[(size_t)csr_src[p] * DIN + t], a);
        }
    }
    gX[(size_t)n * 64 + t] = (t < DIN) ? f2h(a) : (unsigned short)0;
}

// g = A . h  (1024-wide fp16 gather, fp32 accumulate, fp16 output)
__global__ __launch_bounds__(256) void agg_f16_kernel(const unsigned short* __restrict__ h,
                                                      const int* __restrict__ offs,
                                                      const int* __restrict__ csr_src,
                                                      const float* __restrict__ csr_w,
                                                      unsigned short* __restrict__ g) {
    int n = blockIdx.x;
    int t = threadIdx.x;  // 0..255, 4 fp16 each
    float a0 = 0, a1 = 0, a2 = 0, a3 = 0;
    int p0 = offs[n], p1 = offs[n + 1];
    for (int p = p0; p < p1; ++p) {
        int s = csr_src[p];
        float w = csr_w[p];
        ushort4 v = *(const ushort4*)&h[(size_t)s * HID + t * 4];
        a0 = fmaf(w, h2f(v.x), a0);
        a1 = fmaf(w, h2f(v.y), a1);
        a2 = fmaf(w, h2f(v.z), a2);
        a3 = fmaf(w, h2f(v.w), a3);
    }
    ushort4 ov;
    ov.x = f2h(a0); ov.y = f2h(a1); ov.z = f2h(a2); ov.w = f2h(a3);
    *(ushort4*)&g[(size_t)n * HID + t * 4] = ov;
}

// ---------------- fp16 MFMA GEMM, m97-style async staging ----------------
// C[M][N] = [A | optional second half] @ Bt^T, fp32 accumulate.
// A given as two halves Ag (k < khalf) and Ah (k >= khalf), each [M][khalf] fp16
// (pass Ag==Ah and khalf==ktot for a single-array A). Bt is [N][ktot] fp16.
// Block tile 128x128, BK=32, 4 waves (2x2), wave 64x64 = 4x4 MFMA 16x16x32 tiles.
// Staging: global_load_lds width=16 into unpadded LDS [128][32]
// (LDS dest == wave-uniform base + lane*16, as required).
// EPI 0: elu -> fp16 Co (ldc). EPI 1: fp32 -> Co (ldc).

#define GBM 128
#define GBN 128
#define GBK 32

template <int EPI>
__global__ __launch_bounds__(256, 4) void mfma_gemm_kernel(
        const unsigned short* __restrict__ Ag, const unsigned short* __restrict__ Ah,
        const unsigned short* __restrict__ Bt,
        void* __restrict__ Co,
        int M, int N, int ldc, int ktot, int khalf) {
    __shared__ __align__(16) unsigned short sA[GBM * GBK];
    __shared__ __align__(16) unsigned short sB[GBN * GBK];

    const int tid = threadIdx.x;
    const int lane = tid & 63;
    const int wave = tid >> 6;
    const int wm = wave >> 1;
    const int wn = wave & 1;
    const int bm = blockIdx.y * GBM;
    const int bn = blockIdx.x * GBN;

    // staging map: thread t covers row (t>>2)+64p, k-chunk (t&3)*8 halfs.
    // flat LDS offset = p*4096B + t*16B  ->  wave-uniform base + lane*16. OK.
    const int st_r = tid >> 2;
    const int st_kc = (tid & 3) * 8;

    // clamped global rows (avoid OOB reads; dup rows are masked at store)
    int agm[2], bgn[2];
#pragma unroll
    for (int p = 0; p < 2; ++p) {
        int gm = bm + st_r + p * 64;
        agm[p] = gm < M ? gm : M - 1;
        int gn = bn + st_r + p * 64;
        bgn[p] = gn < N ? gn : N - 1;
    }

    const int frow = lane & 15;
    const int fkc = (lane >> 4) * 8;

    floatx4 acc[4][4];
#pragma unroll
    for (int i = 0; i < 4; ++i)
#pragma unroll
        for (int j = 0; j < 4; ++j) acc[i][j] = (floatx4){0.f, 0.f, 0.f, 0.f};

    for (int k0 = 0; k0 < ktot; k0 += GBK) {
        // issue async staging for this K-tile
        const unsigned short* ap = (k0 < khalf) ? Ag : Ah;
        int ka = (k0 < khalf) ? k0 : k0 - khalf;
#pragma unroll
        for (int p = 0; p < 2; ++p) {
            async16(&ap[(size_t)agm[p] * khalf + ka + st_kc],
                    &sA[(p * 64 + st_r) * GBK + st_kc]);
            async16(&Bt[(size_t)bgn[p] * ktot + k0 + st_kc],
                    &sB[(p * 64 + st_r) * GBK + st_kc]);
        }
        __syncthreads();  // drains vmcnt(0): staged data visible

        half8 fa[4], fb[4];
#pragma unroll
        for (int i = 0; i < 4; ++i)
            fa[i] = *(const half8*)&sA[(wm * 64 + i * 16 + frow) * GBK + fkc];
#pragma unroll
        for (int j = 0; j < 4; ++j)
            fb[j] = *(const half8*)&sB[(wn * 64 + j * 16 + frow) * GBK + fkc];
#pragma unroll
        for (int i = 0; i < 4; ++i)
#pragma unroll
            for (int j = 0; j < 4; ++j)
                acc[i][j] = __builtin_amdgcn_mfma_f32_16x16x32_f16(fa[i], fb[j], acc[i][j], 0, 0, 0);
        __syncthreads();  // all waves done reading LDS before next stage
    }

    // C/D layout: col=lane&15, row=(lane>>4)*4+reg
    const int c_r0 = (lane >> 4) * 4;
    const int c_c = lane & 15;
#pragma unroll
    for (int i = 0; i < 4; ++i)
#pragma unroll
        for (int j = 0; j < 4; ++j) {
            int gn = bn + wn * 64 + j * 16 + c_c;
            if (gn >= N) continue;
#pragma unroll
            for (int r = 0; r < 4; ++r) {
                int gm = bm + wm * 64 + i * 16 + c_r0 + r;
                if (gm >= M) continue;
                float v = acc[i][j][r];
                if (EPI == 0) {
                    v = v > 0 ? v : expf(v) - 1.0f;  // elu
                    ((unsigned short*)Co)[(size_t)gm * ldc + gn] = f2h(v);
                } else {
                    ((float*)Co)[(size_t)gm * ldc + gn] = v;
                }
            }
        }
}

// ---------------- launch ----------------

static inline size_t align_up(size_t x, size_t a) { return (x + a - 1) & ~(a - 1); }

extern "C" void kernel_launch(void* const* d_in, const int* in_sizes, int n_in,
                              void* d_out, int out_size, void* d_ws, size_t ws_size,
                              hipStream_t stream) {
    const float* X  = (const float*)d_in[0];
    const int* erow = (const int*)d_in[1];
    const int* ecol = (const int*)d_in[1] + N_EDGES;
    const float* W1 = (const float*)d_in[2];
    const float* W2 = (const float*)d_in[3];
    const float* S2 = (const float*)d_in[4];
    const float* W3 = (const float*)d_in[5];
    const float* S3 = (const float*)d_in[6];
    float* out = (float*)d_out;

    // workspace carve-up
    char* w = (char*)d_ws;
    int* deg     = (int*)w;             w += align_up((size_t)N_NODES * 4, 256);
    int* offs    = (int*)w;             w += align_up((size_t)(N_NODES + 1) * 4, 256);
    int* cursor  = (int*)w;             w += align_up((size_t)N_NODES * 4, 256);
    int* csr_src = (int*)w;             w += align_up((size_t)N_EDGES * 4, 256);
    float* dis   = (float*)w;           w += align_up((size_t)N_NODES * 4, 256);
    float* norm  = (float*)w;           w += align_up((size_t)N_EDGES * 4, 256);
    float* csr_w = (float*)w;           w += align_up((size_t)N_EDGES * 4, 256);
    unsigned short* gXh = (unsigned short*)w; w += align_up((size_t)N_NODES * 64 * 2, 256);
    unsigned short* h1 = (unsigned short*)w;  w += align_up((size_t)N_NODES * HID * 2, 256);
    unsigned short* g  = (unsigned short*)w;  w += align_up((size_t)N_NODES * HID * 2, 256);
    unsigned short* h2 = (unsigned short*)w;  w += align_up((size_t)N_NODES * HID * 2, 256);
    unsigned short* Bt1 = (unsigned short*)w; w += align_up((size_t)HID * 64 * 2, 256);
    unsigned short* Bt2 = (unsigned short*)w; w += align_up((size_t)HID * KCAT * 2, 256);
    unsigned short* Bt3 = (unsigned short*)w; w += align_up((size_t)NCLS * KCAT * 2, 256);

    const int TB = 256;
    int nb_n = (N_NODES + TB - 1) / TB;
    int nb_e = (N_EDGES + TB - 1) / TB;

    // 1. degree / norm / CSR build
    zero_int_kernel<<<nb_n, TB, 0, stream>>>(deg, N_NODES);
    count_deg_kernel<<<nb_e, TB, 0, stream>>>(ecol, deg, N_EDGES);
    compute_dis_kernel<<<nb_n, TB, 0, stream>>>(deg, dis, N_NODES);
    compute_norm_kernel<<<nb_e, TB, 0, stream>>>(erow, ecol, dis, norm, N_EDGES);
    scan_kernel<<<1, 1024, 0, stream>>>(deg, offs, cursor, N_NODES, N_EDGES);
    scatter_kernel<<<nb_e, TB, 0, stream>>>(erow, ecol, norm, cursor, csr_src, csr_w, N_EDGES);

    // 2. weight prep (fp16, transposed)
    w1t_kernel<<<(HID * 64 + 255) / 256, 256, 0, stream>>>(W1, Bt1);
    convert_wt2_kernel<<<(HID * HID + 255) / 256, 256, 0, stream>>>(W2, Bt2, 0);
    convert_wt2_kernel<<<(HID * HID + 255) / 256, 256, 0, stream>>>(S2, Bt2, HID);
    fold3_kernel<<<(NCLS * HID + 255) / 256, 256, 0, stream>>>(W3, Bt3, 0);
    fold3_kernel<<<(NCLS * HID + 255) / 256, 256, 0, stream>>>(S3, Bt3, HID);

    // 3. layer 1: gX = A.X (fp16, K padded to 64) ; h1 = elu(gX @ W1) -> fp16
    aggX_kernel<<<N_NODES, 64, 0, stream>>>(X, offs, csr_src, csr_w, gXh);
    {
        dim3 grid(HID / GBN, (N_NODES + GBM - 1) / GBM);
        mfma_gemm_kernel<0><<<grid, 256, 0, stream>>>(gXh, gXh, Bt1, h1,
                                                      N_NODES, HID, HID, 64, 64);
    }

    // 4. layer 2: g1 = A.h1 ; h2 = elu([g1|h1] @ [W2;S2]) -> fp16
    agg_f16_kernel<<<N_NODES, 256, 0, stream>>>(h1, offs, csr_src, csr_w, g);
    {
        dim3 grid(HID / GBN, (N_NODES + GBM - 1) / GBM);
        mfma_gemm_kernel<0><<<grid, 256, 0, stream>>>(g, h1, Bt2, h2,
                                                      N_NODES, HID, HID, KCAT, HID);
    }

    // 5. layer 3: g2 = A.h2 ; out = [g2|h2] @ [W3bar;S3bar]  (head-mean folded into weights)
    agg_f16_kernel<<<N_NODES, 256, 0, stream>>>(h2, offs, csr_src, csr_w, g);
    {
        dim3 grid(1, (N_NODES + GBM - 1) / GBM);
        mfma_gemm_kernel<1><<<grid, 256, 0, stream>>>(g, h2, Bt3, out,
                                                      N_NODES, NCLS, NCLS, KCAT, HID);
    }
}

// Round 7
// 556.406 us; speedup vs baseline: 5.0046x; 1.0530x over previous
//
#include <hip/hip_runtime.h>
#include <hip/hip_bf16.h>
#include <math.h>

#define N_NODES 20000
#define N_EDGES 320000
#define DIN 50
#define HID 1024
#define NC3 726   // 6*121
#define NCLS 121
#define KCAT 2048

typedef __attribute__((ext_vector_type(8))) _Float16 half8;
typedef __attribute__((ext_vector_type(4))) float floatx4;

__device__ __forceinline__ unsigned short f2h(float v) {
    _Float16 h = (_Float16)v;
    return __builtin_bit_cast(unsigned short, h);
}
__device__ __forceinline__ float h2f(unsigned short u) {
    return (float)__builtin_bit_cast(_Float16, u);
}

// async global->LDS, 16B per lane. LDS dest must equal wave-uniform base + lane*16.
__device__ __forceinline__ void async16(const void* g, void* l) {
    __builtin_amdgcn_global_load_lds(
        (const __attribute__((address_space(1))) void*)g,
        (__attribute__((address_space(3))) void*)l,
        16, 0, 0);
}

// ---------------- CSR build ----------------

__global__ void zero_int_kernel(int* p, int n) {
    int i = blockIdx.x * blockDim.x + threadIdx.x;
    if (i < n) p[i] = 0;
}

__global__ void count_deg_kernel(const int* __restrict__ col, int* __restrict__ deg, int e) {
    int i = blockIdx.x * blockDim.x + threadIdx.x;
    if (i < e) atomicAdd(&deg[col[i]], 1);
}

__global__ void compute_dis_kernel(const int* __restrict__ deg, float* __restrict__ dis, int n) {
    int i = blockIdx.x * blockDim.x + threadIdx.x;
    if (i < n) {
        int d = deg[i];
        dis[i] = d > 0 ? rsqrtf((float)d) : 0.0f;
    }
}

__global__ void compute_norm_kernel(const int* __restrict__ row, const int* __restrict__ col,
                                    const float* __restrict__ dis, float* __restrict__ norm, int e) {
    int i = blockIdx.x * blockDim.x + threadIdx.x;
    if (i < e) norm[i] = dis[row[i]] * dis[col[i]];
}

__global__ __launch_bounds__(1024) void scan_kernel(const int* __restrict__ deg,
                                                    int* __restrict__ offs,
                                                    int* __restrict__ cursor,
                                                    int n, int total) {
    __shared__ int part[1024];
    int t = threadIdx.x;
    const int CH = (n + 1023) / 1024;
    int base0 = t * CH;
    int s = 0;
    for (int i = 0; i < CH; ++i) {
        int idx = base0 + i;
        if (idx < n) s += deg[idx];
    }
    part[t] = s;
    __syncthreads();
    for (int d = 1; d < 1024; d <<= 1) {
        int v = (t >= d) ? part[t - d] : 0;
        __syncthreads();
        part[t] += v;
        __syncthreads();
    }
    int run = part[t] - s;
    for (int i = 0; i < CH; ++i) {
        int idx = base0 + i;
        if (idx < n) {
            offs[idx] = run;
            cursor[idx] = run;
            run += deg[idx];
        }
    }
    if (t == 1023) offs[n] = total;
}

__global__ void scatter_kernel(const int* __restrict__ row, const int* __restrict__ col,
                               const float* __restrict__ norm, int* __restrict__ cursor,
                               int* __restrict__ csr_src, float* __restrict__ csr_w, int e) {
    int i = blockIdx.x * blockDim.x + threadIdx.x;
    if (i < e) {
        int c = col[i];
        int pos = atomicAdd(&cursor[c], 1);
        csr_src[pos] = row[i];
        csr_w[pos] = norm[i];
    }
}

// ---------------- weight prep ----------------

// W1 [50][1024] fp32 -> Bt1 fp16 [1024][64] (transposed, K padded to 64)
__global__ void w1t_kernel(const float* __restrict__ W1, unsigned short* __restrict__ Bt1) {
    int i = blockIdx.x * blockDim.x + threadIdx.x;
    if (i >= HID * 64) return;
    int n = i / 64, k = i - n * 64;
    Bt1[i] = (k < DIN) ? f2h(W1[(size_t)k * HID + n]) : (unsigned short)0;
}

// W [1024][1024] fp32 -> Bt fp16 [1024][2048] at column offset koff (transposed)
__global__ void convert_wt2_kernel(const float* __restrict__ W,
                                   unsigned short* __restrict__ Th, int koff) {
    int i = blockIdx.x * blockDim.x + threadIdx.x;
    if (i >= HID * HID) return;
    int k = i / HID, n = i - k * HID;
    Th[(size_t)n * KCAT + koff + k] = f2h(W[i]);
}

// W [1024][726] fp32 -> head-folded transposed Bt fp16 [121][2048] at column offset koff
__global__ void fold3_kernel(const float* __restrict__ W,
                             unsigned short* __restrict__ Th, int koff) {
    int i = blockIdx.x * blockDim.x + threadIdx.x;
    if (i >= NCLS * HID) return;
    int c = i / HID, k = i - c * HID;
    const float* r = W + (size_t)k * NC3 + c;
    float v = (r[0] + r[121] + r[242] + r[363] + r[484] + r[605]) * (1.0f / 6.0f);
    Th[(size_t)c * KCAT + koff + k] = f2h(v);
}

// ---------------- aggregations ----------------

// gX = A . X  (50-wide fp32 gather -> fp16 out, rows padded to 64)
__global__ __launch_bounds__(64) void aggX_kernel(const float* __restrict__ X,
                                                  const int* __restrict__ offs,
                                                  const int* __restrict__ csr_src,
                                                  const float* __restrict__ csr_w,
                                                  unsigned short* __restrict__ gX) {
    int n = blockIdx.x;
    int t = threadIdx.x;
    float a = 0.0f;
    if (t < DIN) {
        int p0 = offs[n], p1 = offs[n + 1];
        for (int p = p0; p < p1; ++p) {
            a = fmaf(csr_w[p], X[(size_t)csr_src[p] * DIN + t], a);
        }
    }
    gX[(size_t)n * 64 + t] = (t < DIN) ? f2h(a) : (unsigned short)0;
}

// g = A . h  (1024-wide fp16 gather, fp32 accumulate, fp16 output)
__global__ __launch_bounds__(256) void agg_f16_kernel(const unsigned short* __restrict__ h,
                                                      const int* __restrict__ offs,
                                                      const int* __restrict__ csr_src,
                                                      const float* __restrict__ csr_w,
                                                      unsigned short* __restrict__ g) {
    int n = blockIdx.x;
    int t = threadIdx.x;  // 0..255, 4 fp16 each
    float a0 = 0, a1 = 0, a2 = 0, a3 = 0;
    int p0 = offs[n], p1 = offs[n + 1];
    for (int p = p0; p < p1; ++p) {
        int s = csr_src[p];
        float w = csr_w[p];
        ushort4 v = *(const ushort4*)&h[(size_t)s * HID + t * 4];
        a0 = fmaf(w, h2f(v.x), a0);
        a1 = fmaf(w, h2f(v.y), a1);
        a2 = fmaf(w, h2f(v.z), a2);
        a3 = fmaf(w, h2f(v.w), a3);
    }
    ushort4 ov;
    ov.x = f2h(a0); ov.y = f2h(a1); ov.z = f2h(a2); ov.w = f2h(a3);
    *(ushort4*)&g[(size_t)n * HID + t * 4] = ov;
}

// ---------------- fp16 MFMA GEMM: dbuf async pipeline + XOR-swizzled LDS + XCD grouping ----
// C[M][N] = [Ag | Ah] @ Bt^T, fp32 accumulate. A halves each [M][khalf] fp16
// (Ag==Ah, khalf==ktot for single-array A). Bt is [N][ktot] fp16.
// Block tile 128x128, BK=32, 4 waves (2x2), wave 64x64 = 4x4 MFMA 16x16x32 tiles.
// LDS layout: row-major [128][32] halfs, four 8-half chunks of each row permuted:
// chunk c stored at slot c ^ ((row>>1)&3). DMA dest stays base+lane*16 (the per-lane
// GLOBAL source chunk is permuted instead -> same 64B segment, coalesced).
// Grid: 1-D, f%8 selects XCD slab (mchunk M-tiles x all N-tiles per XCD).
// EPI 0: elu -> fp16 Co (ldc). EPI 1: fp32 -> Co (ldc).

#define GBM 128
#define GBN 128
#define GBK 32

template <int EPI>
__global__ __launch_bounds__(256, 4) void mfma_gemm_kernel(
        const unsigned short* __restrict__ Ag, const unsigned short* __restrict__ Ah,
        const unsigned short* __restrict__ Bt,
        void* __restrict__ Co,
        int M, int N, int ldc, int ktot, int khalf,
        int NB, int MB, int mchunk) {
    __shared__ __align__(16) unsigned short sA[2][GBM * GBK];
    __shared__ __align__(16) unsigned short sB[2][GBN * GBK];

    // --- XCD-grouped block swizzle ---
    const int f = blockIdx.x;
    const int xcd = f & 7;
    const int r0 = f >> 3;
    const int nB = r0 % NB;
    const int mi = r0 / NB;
    const int mB = xcd * mchunk + mi;
    if (mB >= MB) return;
    const int bm = mB * GBM;
    const int bn = nB * GBN;

    const int tid = threadIdx.x;
    const int lane = tid & 63;
    const int wave = tid >> 6;
    const int wm = wave >> 1;
    const int wn = wave & 1;

    // staging map: thread t covers row (t>>2)+64p; stored chunk slot t&3;
    // global chunk = (t&3) ^ ((row>>1)&3)  (row+64 has same (row>>1)&3).
    const int st_r = tid >> 2;
    const int st_slot = tid & 3;
    const int st_c = (st_slot ^ ((st_r >> 1) & 3)) * 8;  // global k offset (halfs)
    const int st_lds = st_r * GBK + st_slot * 8;         // + p*64*GBK

    // clamped global rows (avoid OOB reads; dup rows are masked at store)
    int agm[2], bgn[2];
#pragma unroll
    for (int p = 0; p < 2; ++p) {
        int gm = bm + st_r + p * 64;
        agm[p] = gm < M ? gm : M - 1;
        int gn = bn + st_r + p * 64;
        bgn[p] = gn < N ? gn : N - 1;
    }

    // fragment map: row R = base16 + frow; chunk slot (lane>>4) ^ ((frow>>1)&3)
    const int frow = lane & 15;
    const int fkc = (((lane >> 4) ^ ((frow >> 1) & 3))) * 8;

    floatx4 acc[4][4];
#pragma unroll
    for (int i = 0; i < 4; ++i)
#pragma unroll
        for (int j = 0; j < 4; ++j) acc[i][j] = (floatx4){0.f, 0.f, 0.f, 0.f};

    auto issue = [&](int k0, int buf) {  // k0 is the K OFFSET in halfs (multiple of GBK)
        const unsigned short* ap = (k0 < khalf) ? Ag : Ah;
        int ka = (k0 < khalf) ? k0 : k0 - khalf;
#pragma unroll
        for (int p = 0; p < 2; ++p) {
            async16(&ap[(size_t)agm[p] * khalf + ka + st_c],
                    &sA[buf][p * 64 * GBK + st_lds]);
            async16(&Bt[(size_t)bgn[p] * ktot + k0 + st_c],
                    &sB[buf][p * 64 * GBK + st_lds]);
        }
    };

    const int T = ktot / GBK;
    issue(0, 0);

    for (int t = 0; t < T; ++t) {
        __syncthreads();  // drains DMA for tile t (issued one compute-phase ago);
                          // also guards LDS buffer reuse
        if (t + 1 < T) issue((t + 1) * GBK, (t + 1) & 1);  // k0 = (t+1)*GBK (round-6 bug: passed t+1)

        const unsigned short* a_base = sA[t & 1];
        const unsigned short* b_base = sB[t & 1];
        half8 fa[4], fb[4];
#pragma unroll
        for (int i = 0; i < 4; ++i)
            fa[i] = *(const half8*)&a_base[(wm * 64 + i * 16 + frow) * GBK + fkc];
#pragma unroll
        for (int j = 0; j < 4; ++j)
            fb[j] = *(const half8*)&b_base[(wn * 64 + j * 16 + frow) * GBK + fkc];
#pragma unroll
        for (int i = 0; i < 4; ++i)
#pragma unroll
            for (int j = 0; j < 4; ++j)
                acc[i][j] = __builtin_amdgcn_mfma_f32_16x16x32_f16(fa[i], fb[j], acc[i][j], 0, 0, 0);
    }

    // C/D layout: col=lane&15, row=(lane>>4)*4+reg
    const int c_r0 = (lane >> 4) * 4;
    const int c_c = lane & 15;
#pragma unroll
    for (int i = 0; i < 4; ++i)
#pragma unroll
        for (int j = 0; j < 4; ++j) {
            int gn = bn + wn * 64 + j * 16 + c_c;
            if (gn >= N) continue;
#pragma unroll
            for (int r = 0; r < 4; ++r) {
                int gm = bm + wm * 64 + i * 16 + c_r0 + r;
                if (gm >= M) continue;
                float v = acc[i][j][r];
                if (EPI == 0) {
                    v = v > 0 ? v : expf(v) - 1.0f;  // elu
                    ((unsigned short*)Co)[(size_t)gm * ldc + gn] = f2h(v);
                } else {
                    ((float*)Co)[(size_t)gm * ldc + gn] = v;
                }
            }
        }
}

// ---------------- launch ----------------

static inline size_t align_up(size_t x, size_t a) { return (x + a - 1) & ~(a - 1); }

extern "C" void kernel_launch(void* const* d_in, const int* in_sizes, int n_in,
                              void* d_out, int out_size, void* d_ws, size_t ws_size,
                              hipStream_t stream) {
    const float* X  = (const float*)d_in[0];
    const int* erow = (const int*)d_in[1];
    const int* ecol = (const int*)d_in[1] + N_EDGES;
    const float* W1 = (const float*)d_in[2];
    const float* W2 = (const float*)d_in[3];
    const float* S2 = (const float*)d_in[4];
    const float* W3 = (const float*)d_in[5];
    const float* S3 = (const float*)d_in[6];
    float* out = (float*)d_out;

    // workspace carve-up
    char* w = (char*)d_ws;
    int* deg     = (int*)w;             w += align_up((size_t)N_NODES * 4, 256);
    int* offs    = (int*)w;             w += align_up((size_t)(N_NODES + 1) * 4, 256);
    int* cursor  = (int*)w;             w += align_up((size_t)N_NODES * 4, 256);
    int* csr_src = (int*)w;             w += align_up((size_t)N_EDGES * 4, 256);
    float* dis   = (float*)w;           w += align_up((size_t)N_NODES * 4, 256);
    float* norm  = (float*)w;           w += align_up((size_t)N_EDGES * 4, 256);
    float* csr_w = (float*)w;           w += align_up((size_t)N_EDGES * 4, 256);
    unsigned short* gXh = (unsigned short*)w; w += align_up((size_t)N_NODES * 64 * 2, 256);
    unsigned short* h1 = (unsigned short*)w;  w += align_up((size_t)N_NODES * HID * 2, 256);
    unsigned short* g  = (unsigned short*)w;  w += align_up((size_t)N_NODES * HID * 2, 256);
    unsigned short* h2 = (unsigned short*)w;  w += align_up((size_t)N_NODES * HID * 2, 256);
    unsigned short* Bt1 = (unsigned short*)w; w += align_up((size_t)HID * 64 * 2, 256);
    unsigned short* Bt2 = (unsigned short*)w; w += align_up((size_t)HID * KCAT * 2, 256);
    unsigned short* Bt3 = (unsigned short*)w; w += align_up((size_t)NCLS * KCAT * 2, 256);

    const int TB = 256;
    int nb_n = (N_NODES + TB - 1) / TB;
    int nb_e = (N_EDGES + TB - 1) / TB;

    // 1. degree / norm / CSR build
    zero_int_kernel<<<nb_n, TB, 0, stream>>>(deg, N_NODES);
    count_deg_kernel<<<nb_e, TB, 0, stream>>>(ecol, deg, N_EDGES);
    compute_dis_kernel<<<nb_n, TB, 0, stream>>>(deg, dis, N_NODES);
    compute_norm_kernel<<<nb_e, TB, 0, stream>>>(erow, ecol, dis, norm, N_EDGES);
    scan_kernel<<<1, 1024, 0, stream>>>(deg, offs, cursor, N_NODES, N_EDGES);
    scatter_kernel<<<nb_e, TB, 0, stream>>>(erow, ecol, norm, cursor, csr_src, csr_w, N_EDGES);

    // 2. weight prep (fp16, transposed)
    w1t_kernel<<<(HID * 64 + 255) / 256, 256, 0, stream>>>(W1, Bt1);
    convert_wt2_kernel<<<(HID * HID + 255) / 256, 256, 0, stream>>>(W2, Bt2, 0);
    convert_wt2_kernel<<<(HID * HID + 255) / 256, 256, 0, stream>>>(S2, Bt2, HID);
    fold3_kernel<<<(NCLS * HID + 255) / 256, 256, 0, stream>>>(W3, Bt3, 0);
    fold3_kernel<<<(NCLS * HID + 255) / 256, 256, 0, stream>>>(S3, Bt3, HID);

    const int MB = (N_NODES + GBM - 1) / GBM;   // 157
    const int mchunk = (MB + 7) / 8;            // 20
    const int NB2 = HID / GBN;                  // 8

    // 3. layer 1: gX = A.X (fp16, K padded to 64) ; h1 = elu(gX @ W1) -> fp16
    aggX_kernel<<<N_NODES, 64, 0, stream>>>(X, offs, csr_src, csr_w, gXh);
    mfma_gemm_kernel<0><<<8 * mchunk * NB2, 256, 0, stream>>>(
        gXh, gXh, Bt1, h1, N_NODES, HID, HID, 64, 64, NB2, MB, mchunk);

    // 4. layer 2: g1 = A.h1 ; h2 = elu([g1|h1] @ [W2;S2]) -> fp16
    agg_f16_kernel<<<N_NODES, 256, 0, stream>>>(h1, offs, csr_src, csr_w, g);
    mfma_gemm_kernel<0><<<8 * mchunk * NB2, 256, 0, stream>>>(
        g, h1, Bt2, h2, N_NODES, HID, HID, KCAT, HID, NB2, MB, mchunk);

    // 5. layer 3: g2 = A.h2 ; out = [g2|h2] @ [W3bar;S3bar]  (head-mean folded into weights)
    agg_f16_kernel<<<N_NODES, 256, 0, stream>>>(h2, offs, csr_src, csr_w, g);
    mfma_gemm_kernel<1><<<8 * mchunk * 1, 256, 0, stream>>>(
        g, h2, Bt3, out, N_NODES, NCLS, NCLS, KCAT, HID, 1, MB, mchunk);
}